// Round 15
// baseline (1618.638 us; speedup 1.0000x reference)
//
#include <hip/hip_runtime.h>
#include <math.h>

#define THREADS 256
typedef __attribute__((ext_vector_type(2))) float f32x2;

__device__ __forceinline__ float silu_f(float v) {
    return v / (1.f + __expf(-v));
}

// packed fp32 fma (v_pk_fma_f32), weight pair in SGPRs (one scalar source is
// legal on VOP3P), pixel pair broadcast via op_sel on src0.
__device__ __forceinline__ void pk_fma_lo_s(f32x2& d, f32x2 a, f32x2 b) {
    asm("v_pk_fma_f32 %0, %1, %2, %0 op_sel:[0,0,0] op_sel_hi:[0,1,1]"
        : "+v"(d) : "v"(a), "s"(b));
}
__device__ __forceinline__ void pk_fma_hi_s(f32x2& d, f32x2 a, f32x2 b) {
    asm("v_pk_fma_f32 %0, %1, %2, %0 op_sel:[1,0,0] op_sel_hi:[1,1,1]"
        : "+v"(d) : "v"(a), "s"(b));
}

// ---------------------------------------------------------------------------
// Weight transpose: [co][ci][k2] -> [ci][k2][co]
// ---------------------------------------------------------------------------
struct TEnt { const float* src; int dst; int cin; int cout; int k2; int base; int n; };
struct TTab { TEnt e[40]; int total; };

__global__ __launch_bounds__(THREADS)
void transpose_w_k(TTab t, float* __restrict__ tw) {
    const int i = blockIdx.x * THREADS + threadIdx.x;
    if (i >= t.total) return;
    int j = 0;
    while (i >= t.e[j].base + t.e[j].n) ++j;
    const TEnt e = t.e[j];
    const int local = i - e.base;
    const int co  = local % e.cout;
    const int tmp = local / e.cout;
    const int k   = tmp % e.k2;
    const int ci  = tmp / e.k2;
    tw[e.dst + local] = e.src[(co * e.cin + ci) * e.k2 + k];
}

// aligned-chunk row loader; interior chunks skip per-lane x checks.
template<int KS, int PX>
__device__ __forceinline__ void load_row(float* __restrict__ rr,
                                         const float* __restrict__ rp,
                                         bool vy, int x0, int W)
{
    constexpr int PAD = (KS - 1) / 2;
    constexpr int RW = PX + KS - 1;
#pragma unroll
    for (int q = -1; q <= PX / 4; ++q) {
        if (4 * q + 3 + PAD < 0 || 4 * q + PAD >= RW) continue;
        const int xs = x0 + 4 * q;
        const bool safe = (q >= 0) && (4 * q + 3 < PX);   // compile-time per q
        float vc[4] = {0.f, 0.f, 0.f, 0.f};
        if (safe) {
            if (vy) {
                const float4 v = *reinterpret_cast<const float4*>(rp + xs);
                vc[0] = v.x; vc[1] = v.y; vc[2] = v.z; vc[3] = v.w;
            }
        } else if (vy && xs >= 0 && xs + 4 <= W) {
            const float4 v = *reinterpret_cast<const float4*>(rp + xs);
            vc[0] = v.x; vc[1] = v.y; vc[2] = v.z; vc[3] = v.w;
        } else if (vy) {
#pragma unroll
            for (int c = 0; c < 4; ++c)
                vc[c] = ((unsigned)(xs + c) < (unsigned)W) ? rp[xs + c] : 0.f;
        }
#pragma unroll
        for (int c = 0; c < 4; ++c) {
            const int t = 4 * q + c + PAD;
            if (t >= 0 && t < RW) rr[t] = vc[c];
        }
    }
}

// ---------------------------------------------------------------------------
// Per-channel body, SGPR-weight variant. Weights come from GLOBAL via
// uniform-address loads (s_load -> SGPRs, scalar cache; LDS pipe untouched).
// Double-buffered one tap ahead; K2 odd keeps buffer parity continuous
// across the channel boundary. Round-2 lesson inverted: scalar weights are
// fine when the live set is 2 taps (<=36 SGPRs) and taps are fenced.
// ---------------------------------------------------------------------------
template<int CIN, int COUT, int KS, int PX, int PHASE, int RW2, int NP>
__device__ __forceinline__ void chan_body(
    const float* __restrict__ ip0, const float* __restrict__ wz,
    int cl, int y, int x0, int W, int H, int lw, int total,
    f32x2 (&r2)[2][RW2], f32x2 (&wb)[2][NP], f32x2 (&acc)[NP][PX])
{
    constexpr int PAD = (KS - 1) / 2;
    constexpr int K2 = KS * KS;
    static_assert(K2 % 2 == 1, "parity continuity needs odd K2");
#pragma unroll
    for (int ky = 0; ky < KS; ++ky) {
        {
            const bool last = (ky + 1 == KS);
            const int ncl = cl + (last ? 1 : 0);
            const int nky = last ? 0 : (ky + 1);
            if (!last || ncl < CIN) {
                const int yy = y + nky - PAD;
                load_row<KS, PX>((float*)r2[(PHASE + ky + 1) & 1],
                                 ip0 + (size_t)ncl * total + (yy << lw),
                                 (unsigned)yy < (unsigned)H, x0, W);
            }
        }
#pragma unroll
        for (int kx = 0; kx < KS; ++kx) {
            const int t = ky * KS + kx;
            const int wc = (PHASE + t) & 1;
            if (t + 1 < K2 || cl + 1 < CIN) {
                const f32x2* __restrict__ nx =
                    (const f32x2*)(wz + (size_t)(cl * K2 + t + 1) * COUT);
#pragma unroll
                for (int p = 0; p < NP; ++p) wb[wc ^ 1][p] = nx[p];
            }
#pragma unroll
            for (int p = 0; p < NP; ++p) {
                const f32x2 wp = wb[wc][p];
#pragma unroll
                for (int j = 0; j < PX; ++j) {
                    const int e = kx + j;
                    if (e & 1) pk_fma_hi_s(acc[p][j], r2[(PHASE + ky) & 1][e >> 1], wp);
                    else       pk_fma_lo_s(acc[p][j], r2[(PHASE + ky) & 1][e >> 1], wp);
                }
            }
            __builtin_amdgcn_sched_barrier(0);
        }
    }
}

// ---------------------------------------------------------------------------
// Sliced direct conv2d, 1-D grid with XCD-grouped decode (round-14: slices
// of one (xb,b) group share lin%8 -> same XCD L2; FETCH halved). SGPR
// weights -> zero LDS. Round-12 lesson: acc <= ~64 f32x2.
// ---------------------------------------------------------------------------
template<int CIN, int COUT, int KS, bool ACT, int PX>
__global__ __launch_bounds__(THREADS)
void conv_sl_k(const float* __restrict__ in, const float* __restrict__ wt,
               const float* __restrict__ bias, float* __restrict__ out,
               int H, int lw, int bs_in, int bs_out, int nb, int nz)
{
    constexpr int PAD = (KS - 1) / 2;
    constexpr int K2 = KS * KS;
    constexpr int NP = COUT / 2;
    constexpr int RW = PX + KS - 1;
    constexpr int RW2 = (RW + 1) / 2;
    static_assert(CIN % 2 == 0 && COUT % 2 == 0 && PX % 4 == 0, "");

    const int lin = blockIdx.x;
    const int r8 = lin & 7;
    int q = lin >> 3;
    const int z = q % nz; q /= nz;
    const int g = q * 8 + r8;
    const int b = g % nb;
    const int xb = g / nb;

    const float* __restrict__ wz = wt + (size_t)z * (CIN * K2 * COUT);
    const int W = 1 << lw;
    const int total = H << lw;
    const int idx = (xb * THREADS + threadIdx.x) * PX;
    const float* ip0 = in + (size_t)b * bs_in;
    float* op = out + (size_t)b * bs_out + (size_t)z * COUT * total;
    const int x0 = idx & (W - 1);
    const int y  = idx >> lw;

    f32x2 acc[NP][PX];
#pragma unroll
    for (int p = 0; p < NP; ++p) {
        f32x2 bb;
        bb.x = bias[z * COUT + 2 * p];
        bb.y = bias[z * COUT + 2 * p + 1];
#pragma unroll
        for (int j = 0; j < PX; ++j) acc[p][j] = bb;
    }

    f32x2 r2[2][RW2];
    f32x2 wb[2][NP];
    {
        const int yy = y - PAD;
        load_row<KS, PX>((float*)r2[0], ip0 + (yy << lw),
                         (unsigned)yy < (unsigned)H, x0, W);
        const f32x2* __restrict__ w0 = (const f32x2*)wz;
#pragma unroll
        for (int p = 0; p < NP; ++p) wb[0][p] = w0[p];
    }

#pragma unroll 1
    for (int c2 = 0; c2 < CIN / 2; ++c2) {
        chan_body<CIN, COUT, KS, PX, 0, RW2, NP>(ip0, wz, 2 * c2,     y, x0, W, H, lw, total, r2, wb, acc);
        chan_body<CIN, COUT, KS, PX, 1, RW2, NP>(ip0, wz, 2 * c2 + 1, y, x0, W, H, lw, total, r2, wb, acc);
    }

#pragma unroll
    for (int p = 0; p < NP; ++p) {
#pragma unroll
        for (int h = 0; h < 2; ++h) {
            const int co = 2 * p + h;
#pragma unroll
            for (int j4 = 0; j4 < PX / 4; ++j4) {
                float4 v;
                float a0 = h ? acc[p][4 * j4 + 0].y : acc[p][4 * j4 + 0].x;
                float a1 = h ? acc[p][4 * j4 + 1].y : acc[p][4 * j4 + 1].x;
                float a2 = h ? acc[p][4 * j4 + 2].y : acc[p][4 * j4 + 2].x;
                float a3 = h ? acc[p][4 * j4 + 3].y : acc[p][4 * j4 + 3].x;
                v.x = ACT ? silu_f(a0) : a0;
                v.y = ACT ? silu_f(a1) : a1;
                v.z = ACT ? silu_f(a2) : a2;
                v.w = ACT ? silu_f(a3) : a3;
                *reinterpret_cast<float4*>(op + (size_t)co * total + idx + 4 * j4) = v;
            }
        }
    }
}

// ---------------------------------------------------------------------------
// Generic direct conv2d (SGPR weights, zero LDS), grid.y = batch.
// ---------------------------------------------------------------------------
template<int CIN, int COUT, int KS, bool ACT, int PX>
__global__ __launch_bounds__(THREADS)
void conv_k(const float* __restrict__ in, const float* __restrict__ wt,
            const float* __restrict__ bias, float* __restrict__ out,
            int H, int lw, int bs_in, int bs_out)
{
    constexpr int PAD = (KS - 1) / 2;
    constexpr int K2 = KS * KS;
    constexpr int NP = COUT / 2;
    constexpr int RW = PX + KS - 1;
    constexpr int RW2 = (RW + 1) / 2;
    static_assert(COUT % 2 == 0, "");

    const int W = 1 << lw;
    const int total = H << lw;
    const int idx = (blockIdx.x * THREADS + threadIdx.x) * PX;
    const float* ip0 = in + (size_t)blockIdx.y * bs_in;
    float* op = out + (size_t)blockIdx.y * bs_out;
    const int x0 = idx & (W - 1);
    const int y  = idx >> lw;

    f32x2 acc[NP][PX];
#pragma unroll
    for (int p = 0; p < NP; ++p) {
        f32x2 bb;
        bb.x = bias[2 * p];
        bb.y = bias[2 * p + 1];
#pragma unroll
        for (int j = 0; j < PX; ++j) acc[p][j] = bb;
    }

#pragma unroll 1
    for (int cl = 0; cl < CIN; ++cl) {
        const float* __restrict__ row0 = ip0 + (size_t)cl * total;
        f32x2 r2[KS][RW2];
#pragma unroll
        for (int ky = 0; ky < KS; ++ky) {
            const int yy = y + ky - PAD;
            load_row<KS, PX>((float*)r2[ky], row0 + (yy << lw),
                             (unsigned)yy < (unsigned)H, x0, W);
        }
        const float* __restrict__ wc0 = wt + (size_t)cl * K2 * COUT;
        f32x2 wb[2][NP];
        {
            const f32x2* __restrict__ w0 = (const f32x2*)wc0;
#pragma unroll
            for (int p = 0; p < NP; ++p) wb[0][p] = w0[p];
        }
#pragma unroll
        for (int t = 0; t < K2; ++t) {
            const int ky = t / KS, kx = t % KS;
            if (t + 1 < K2) {
                const f32x2* __restrict__ nx = (const f32x2*)(wc0 + (t + 1) * COUT);
#pragma unroll
                for (int p = 0; p < NP; ++p) wb[(t + 1) & 1][p] = nx[p];
            }
#pragma unroll
            for (int p = 0; p < NP; ++p) {
                const f32x2 wp = wb[t & 1][p];
#pragma unroll
                for (int j = 0; j < PX; ++j) {
                    const int e = kx + j;
                    if (e & 1) pk_fma_hi_s(acc[p][j], r2[ky][e >> 1], wp);
                    else       pk_fma_lo_s(acc[p][j], r2[ky][e >> 1], wp);
                }
            }
            __builtin_amdgcn_sched_barrier(0);
        }
    }

#pragma unroll
    for (int p = 0; p < NP; ++p) {
#pragma unroll
        for (int h = 0; h < 2; ++h) {
            const int co = 2 * p + h;
            if (PX == 2) {
                float2 v;
                float a0 = h ? acc[p][0].y : acc[p][0].x;
                float a1 = h ? acc[p][1].y : acc[p][1].x;
                v.x = ACT ? silu_f(a0) : a0;
                v.y = ACT ? silu_f(a1) : a1;
                *reinterpret_cast<float2*>(op + (size_t)co * total + idx) = v;
            } else {
#pragma unroll
                for (int j4 = 0; j4 < PX / 4; ++j4) {
                    float4 v;
                    float a0 = h ? acc[p][4 * j4 + 0].y : acc[p][4 * j4 + 0].x;
                    float a1 = h ? acc[p][4 * j4 + 1].y : acc[p][4 * j4 + 1].x;
                    float a2 = h ? acc[p][4 * j4 + 2].y : acc[p][4 * j4 + 2].x;
                    float a3 = h ? acc[p][4 * j4 + 3].y : acc[p][4 * j4 + 3].x;
                    v.x = ACT ? silu_f(a0) : a0;
                    v.y = ACT ? silu_f(a1) : a1;
                    v.z = ACT ? silu_f(a2) : a2;
                    v.w = ACT ? silu_f(a3) : a3;
                    *reinterpret_cast<float4*>(op + (size_t)co * total + idx + 4 * j4) = v;
                }
            }
        }
    }
}

// ---------------------------------------------------------------------------
// DeformConv2d: 3x3, stride 1, pad 1, no bias. groups=2, offset groups=2.
// ---------------------------------------------------------------------------
template<int CIN, int COUT>
__global__ __launch_bounds__(THREADS)
void dconv_k(const float* __restrict__ in, const float* __restrict__ off,
             const float* __restrict__ twg0, const float* __restrict__ twg1,
             float* __restrict__ out,
             int H, int lw, int bs_in, int bs_off, int bs_out)
{
    constexpr int K = 9;
    constexpr int OG = 2;
    constexpr int COG = CIN / OG;
    constexpr int COUTG = COUT / 2;
    constexpr int NWG = COG * K * COUTG;
    __shared__ float sw[2 * NWG];
    for (int i = threadIdx.x; i < 2 * NWG; i += THREADS)
        sw[i] = (i < NWG) ? twg0[i] : twg1[i - NWG];
    __syncthreads();

    const int W = 1 << lw;
    const int total = H << lw;
    const int idx = blockIdx.x * THREADS + threadIdx.x;
    const float* ip0 = in + (size_t)blockIdx.y * bs_in;
    const float* offp = off + (size_t)blockIdx.y * bs_off;
    float* op = out + (size_t)blockIdx.y * bs_out;
    const int x = idx & (W - 1);
    const int y = idx >> lw;

    float acc[COUT];
#pragma unroll
    for (int co = 0; co < COUT; ++co) acc[co] = 0.f;

#pragma unroll
    for (int og = 0; og < OG; ++og) {
#pragma unroll
        for (int k = 0; k < K; ++k) {
            const int ki = k / 3 - 1;
            const int kj = k % 3 - 1;
            const float dy = offp[(size_t)(((og * K + k) * 2 + 0)) * total + idx];
            const float dx = offp[(size_t)(((og * K + k) * 2 + 1)) * total + idx];
            const float py = dy + (float)(y + ki);
            const float px = dx + (float)(x + kj);
            const float y0f = floorf(py), x0f = floorf(px);
            const float ly = py - y0f, lx = px - x0f;
            const int y0 = (int)y0f, x0 = (int)x0f;
            const int y1 = y0 + 1, x1 = x0 + 1;
            const bool vy0 = (unsigned)y0 < (unsigned)H;
            const bool vy1 = (unsigned)y1 < (unsigned)H;
            const bool vx0 = (unsigned)x0 < (unsigned)W;
            const bool vx1 = (unsigned)x1 < (unsigned)W;
            const int cy0 = min(max(y0, 0), H - 1), cy1 = min(max(y1, 0), H - 1);
            const int cx0 = min(max(x0, 0), W - 1), cx1 = min(max(x1, 0), W - 1);
            const int i00 = (cy0 << lw) + cx0, i01 = (cy0 << lw) + cx1;
            const int i10 = (cy1 << lw) + cx0, i11 = (cy1 << lw) + cx1;
            const float f00 = (vy0 && vx0) ? (1.f - ly) * (1.f - lx) : 0.f;
            const float f01 = (vy0 && vx1) ? (1.f - ly) * lx : 0.f;
            const float f10 = (vy1 && vx0) ? ly * (1.f - lx) : 0.f;
            const float f11 = (vy1 && vx1) ? ly * lx : 0.f;
            const float* swg = &sw[og * NWG];
#pragma unroll
            for (int c = 0; c < COG; ++c) {
                const float* __restrict__ ip = ip0 + (size_t)(og * COG + c) * total;
                const float v = f00 * ip[i00] + f01 * ip[i01]
                              + f10 * ip[i10] + f11 * ip[i11];
                const float* __restrict__ wr = &swg[(c * K + k) * COUTG];
#pragma unroll
                for (int col = 0; col < COUTG; ++col)
                    acc[og * COUTG + col] = fmaf(v, wr[col], acc[og * COUTG + col]);
            }
        }
    }

#pragma unroll
    for (int co = 0; co < COUT; ++co)
        op[(size_t)co * total + idx] = acc[co];
}

// 2x2 average pool.
__global__ __launch_bounds__(THREADS)
void avgpool_k(const float* __restrict__ in, float* __restrict__ out,
               int n, int lt, int lwo, int bsi, int bso)
{
    const int idx = blockIdx.x * THREADS + threadIdx.x;
    if (idx >= n) return;
    const float* ip0 = in + (size_t)blockIdx.y * bsi;
    float* op = out + (size_t)blockIdx.y * bso;
    const int c = idx >> lt;
    const int r = idx & ((1 << lt) - 1);
    const int oy = r >> lwo;
    const int ox = r & ((1 << lwo) - 1);
    const int Wi = 2 << lwo;
    const float* ip = ip0 + ((size_t)c << (lt + 2)) + ((size_t)(2 * oy) << (lwo + 1)) + 2 * ox;
    const float2 t = *reinterpret_cast<const float2*>(ip);
    const float2 b = *reinterpret_cast<const float2*>(ip + Wi);
    op[idx] = 0.25f * (t.x + t.y + b.x + b.y);
}

// Bilinear 2x upsample, align_corners=True.
__global__ __launch_bounds__(THREADS)
void up2x_k(const float* __restrict__ in, float* __restrict__ out,
            int n, int lt, int lwo, int Hin, int bsi, int bso)
{
    const int idx = blockIdx.x * THREADS + threadIdx.x;
    if (idx >= n) return;
    const float* ip0 = in + (size_t)blockIdx.y * bsi;
    float* op = out + (size_t)blockIdx.y * bso;
    const int c = idx >> lt;
    const int r = idx & ((1 << lt) - 1);
    const int oy = r >> lwo;
    const int ox = r & ((1 << lwo) - 1);
    const int W = 1 << (lwo - 1);
    const int H = Hin;
    const float s = (float)(H - 1) / (float)(2 * H - 1);
    const float fy = (float)oy * s;
    const float fx = (float)ox * s;
    const int y0 = (int)fy;
    const int x0 = (int)fx;
    const int y1 = min(y0 + 1, H - 1);
    const int x1 = min(x0 + 1, W - 1);
    const float wy = fy - (float)y0;
    const float wx = fx - (float)x0;
    const float* ip = ip0 + ((size_t)c << (lt - 2));
    const float v00 = ip[y0 * W + x0], v01 = ip[y0 * W + x1];
    const float v10 = ip[y1 * W + x0], v11 = ip[y1 * W + x1];
    op[idx] = (v00 * (1.f - wy) + v10 * wy) * (1.f - wx)
            + (v01 * (1.f - wy) + v11 * wy) * wx;
}

// strided batched d2d copy (float4 granularity)
__global__ __launch_bounds__(THREADS)
void copy_k(float4* __restrict__ dst, const float4* __restrict__ src,
            int n4, int bsd, int bss)
{
    const int i = blockIdx.x * THREADS + threadIdx.x;
    if (i >= n4) return;
    dst[(size_t)blockIdx.y * bsd + i] = src[(size_t)blockIdx.y * bss + i];
}

// ---------------------------------------------------------------------------

extern "C" void kernel_launch(void* const* d_in, const int* in_sizes, int n_in,
                              void* d_out, int out_size, void* d_ws, size_t ws_size,
                              hipStream_t stream) {
    const float* x      = (const float*)d_in[0];
    const float* eo1_b1 = (const float*)d_in[2];
    const float* eo1_b2 = (const float*)d_in[4];
    const float* c1d_b1 = (const float*)d_in[7];
    const float* c1d_b2 = (const float*)d_in[9];
    const float* eo2_b1 = (const float*)d_in[11];
    const float* eo2_b2 = (const float*)d_in[13];
    const float* c2d_b1 = (const float*)d_in[16];
    const float* c2d_b2 = (const float*)d_in[18];
    const float* eo3_b1 = (const float*)d_in[20];
    const float* eo3_b2 = (const float*)d_in[22];
    const float* c3d_b1 = (const float*)d_in[25];
    const float* c3d_b2 = (const float*)d_in[27];
    const float* up2_b  = (const float*)d_in[29];
    const float* c2u_b1 = (const float*)d_in[31];
    const float* c2u_b2 = (const float*)d_in[33];
    const float* up1_b  = (const float*)d_in[35];
    const float* c1u_b1 = (const float*)d_in[37];
    const float* c1u_b2 = (const float*)d_in[39];

    float* out = (float*)d_out;
    float* wsf = (float*)d_ws;

    constexpr int H1 = 512, A1 = H1 * H1;
    constexpr int H2 = 256, A2 = H2 * H2;
    constexpr int H3 = 128, A3 = H3 * H3;
    constexpr int TW_FLOATS = 81920;
    constexpr int SLOT = 58 * A1;

    // ---- transposed-weight table (round-11 shape): 34 conv + 6 dconv ----
    const int widx[34]  = {1, 1, 1,  3, 3, 3, 3, 3,  6, 8,
                           10, 10, 10,  12, 12, 12, 12, 12,  15, 17,
                           19,  21, 21, 21, 21, 21,  24, 26,
                           28, 30, 32, 34, 36, 38};
    const int wcin[34]  = {4, 4, 4,  18, 18, 18, 18, 18,  2, 4,
                           8, 8, 8,  18, 18, 18, 18, 18,  8, 12,
                           16,  18, 18, 18, 18, 18,  16, 14,
                           12, 28, 16, 8, 16, 8};
    const int wcout[34] = {6, 6, 6,  8, 8, 8, 8, 4,  4, 8,
                           6, 6, 6,  8, 8, 8, 8, 4,  12, 16,
                           18,  8, 8, 8, 8, 4,  14, 12,
                           12, 16, 8, 8, 8, 2};
    const int wk2[34]   = {25, 25, 25,  25, 25, 25, 25, 25,  9, 9,
                           25, 25, 25,  25, 25, 25, 25, 25,  9, 9,
                           25,  25, 25, 25, 25, 25,  9, 9,
                           9, 9, 9, 9, 9, 9};
    const int wsoff[34] = {0, 600, 1200,  0, 3600, 7200, 10800, 14400,  0, 0,
                           0, 1200, 2400,  0, 3600, 7200, 10800, 14400,  0, 0,
                           0,  0, 3600, 7200, 10800, 14400,  0, 0,
                           0, 0, 0, 0, 0, 0};
    const int cont[34]  = {1, 1, 0,  1, 1, 1, 0, 0,  0, 0,
                           1, 1, 0,  1, 1, 1, 0, 0,  0, 0,
                           0,  1, 1, 1, 0, 0,  0, 0,
                           0, 0, 0, 0, 0, 0};
    TTab tab;
    const float* tw[40];
    int off = 0, base = 0;
    for (int i = 0; i < 34; ++i) {
        const int n = wcin[i] * wcout[i] * wk2[i];
        tab.e[i].src = (const float*)d_in[widx[i]] + wsoff[i];
        tab.e[i].dst = off; tab.e[i].cin = wcin[i]; tab.e[i].cout = wcout[i];
        tab.e[i].k2 = wk2[i]; tab.e[i].base = base; tab.e[i].n = n;
        tw[i] = wsf + off;
        off = cont[i] ? (off + n) : ((off + n + 63) & ~63);
        base += n;
    }
    const int didx[3]   = {5, 14, 23};
    const int dcoutg[3] = {1, 4, 8};
    const int dcpg[3]   = {2, 4, 8};
    for (int i = 0; i < 3; ++i) {
        for (int g = 0; g < 2; ++g) {
            const int e = 34 + 2 * i + g;
            const int n = dcoutg[i] * dcpg[i] * 9;
            tab.e[e].src = (const float*)d_in[didx[i]] + (size_t)g * n;
            tab.e[e].dst = off; tab.e[e].cin = dcpg[i]; tab.e[e].cout = dcoutg[i];
            tab.e[e].k2 = 9; tab.e[e].base = base; tab.e[e].n = n;
            tw[e] = wsf + off;
            off = (off + n + 63) & ~63;
            base += n;
        }
    }
    tab.total = base;
    transpose_w_k<<<(base + THREADS - 1) / THREADS, THREADS, 0, stream>>>(tab, wsf);

    int B = 4;
    while (B > 1 && ws_size < ((size_t)TW_FLOATS + (size_t)B * SLOT) * sizeof(float)) B >>= 1;

    auto run_all = [&](int Bc, float* slot, int SB,
                       const float* xin, int xbs, float* outp, int obs) {
        float* S0 = slot;
        float* S1 = S0 + 36 * A1;
        float* S2 = S1 + 18 * A1;
        float* P  = S2 + 2 * A1;
        float* L1 = S1 + 10 * A1;
        float* L2 = S0 + 32 * A1;
        auto gs = [&](int n, int px, int z) { return dim3((n / (px * THREADS)) * Bc * z); };
        auto gp = [&](int n, int px) { return dim3(n / (px * THREADS), Bc); };
        auto g1 = [&](int n) { return dim3((n + THREADS - 1) / THREADS, Bc); };

        // ---- level 1 down ----
        conv_sl_k<4, 6, 5, false, 8><<<gs(A1, 8, 3), THREADS, 0, stream>>>(xin, tw[0], eo1_b1, S1, H1, 9, xbs, SB, Bc, 3);
        conv_sl_k<18, 8, 5, false, 8><<<gs(A1, 8, 4), THREADS, 0, stream>>>(S1, tw[3], eo1_b2, S0, H1, 9, SB, SB, Bc, 4);
        conv_sl_k<18, 4, 5, false, 8><<<gs(A1, 8, 1), THREADS, 0, stream>>>(S1, tw[7], eo1_b2 + 32, S0 + 32 * A1, H1, 9, SB, SB, Bc, 1);
        dconv_k<4, 2><<<g1(A1), THREADS, 0, stream>>>(xin, S0, tw[34], tw[35], S2, H1, 9, xbs, SB, SB);
        conv_k<2, 4, 3, true, 8><<<gp(A1, 8), THREADS, 0, stream>>>(S2, tw[8], c1d_b1, S1, H1, 9, SB, SB);
        conv_k<4, 8, 3, true, 8><<<gp(A1, 8), THREADS, 0, stream>>>(S1, tw[9], c1d_b2, L1, H1, 9, SB, SB);
        avgpool_k<<<g1(8 * A2), THREADS, 0, stream>>>(L1, P, 8 * A2, 16, 8, SB, SB);

        // ---- level 2 down ----
        conv_sl_k<8, 6, 5, false, 8><<<gs(A2, 8, 3), THREADS, 0, stream>>>(P, tw[10], eo2_b1, S1, H2, 8, SB, SB, Bc, 3);
        conv_sl_k<18, 8, 5, false, 8><<<gs(A2, 8, 4), THREADS, 0, stream>>>(S1, tw[13], eo2_b2, S0, H2, 8, SB, SB, Bc, 4);
        conv_sl_k<18, 4, 5, false, 8><<<gs(A2, 8, 1), THREADS, 0, stream>>>(S1, tw[17], eo2_b2 + 32, S0 + 32 * A2, H2, 8, SB, SB, Bc, 1);
        dconv_k<8, 8><<<g1(A2), THREADS, 0, stream>>>(P, S0, tw[36], tw[37], S2, H2, 8, SB, SB, SB);
        conv_k<8, 12, 3, true, 4><<<gp(A2, 4), THREADS, 0, stream>>>(S2, tw[18], c2d_b1, S1, H2, 8, SB, SB);
        conv_k<12, 16, 3, true, 4><<<gp(A2, 4), THREADS, 0, stream>>>(S1, tw[19], c2d_b2, L2, H2, 8, SB, SB);
        avgpool_k<<<g1(16 * A3), THREADS, 0, stream>>>(L2, P, 16 * A3, 14, 7, SB, SB);

        // ---- level 3 (bottleneck) ----
        conv_k<16, 18, 5, false, 2><<<gp(A3, 2), THREADS, 0, stream>>>(P, tw[20], eo3_b1, S1, H3, 7, SB, SB);
        conv_sl_k<18, 8, 5, false, 4><<<gs(A3, 4, 4), THREADS, 0, stream>>>(S1, tw[21], eo3_b2, S0, H3, 7, SB, SB, Bc, 4);
        conv_sl_k<18, 4, 5, false, 4><<<gs(A3, 4, 1), THREADS, 0, stream>>>(S1, tw[25], eo3_b2 + 32, S0 + 32 * A3, H3, 7, SB, SB, Bc, 1);
        dconv_k<16, 16><<<g1(A3), THREADS, 0, stream>>>(P, S0, tw[38], tw[39], S2, H3, 7, SB, SB, SB);
        conv_k<16, 14, 3, true, 2><<<gp(A3, 2), THREADS, 0, stream>>>(S2, tw[26], c3d_b1, S1, H3, 7, SB, SB);
        conv_k<14, 12, 3, true, 2><<<gp(A3, 2), THREADS, 0, stream>>>(S1, tw[27], c3d_b2, S2, H3, 7, SB, SB);

        // ---- up path level 2 ----
        up2x_k<<<g1(12 * A2), THREADS, 0, stream>>>(S2, S0, 12 * A2, 16, 8, H3, SB, SB);
        conv_k<12, 12, 3, true, 4><<<gp(A2, 4), THREADS, 0, stream>>>(S0, tw[28], up2_b, S1, H2, 8, SB, SB);
        copy_k<<<g1(4 * A2), THREADS, 0, stream>>>((float4*)(S1 + 12 * A2), (const float4*)L2,
                                                   4 * A2, SB / 4, SB / 4);
        conv_k<28, 16, 3, true, 4><<<gp(A2, 4), THREADS, 0, stream>>>(S1, tw[29], c2u_b1, S0, H2, 8, SB, SB);
        conv_k<16, 8, 3, true, 4><<<gp(A2, 4), THREADS, 0, stream>>>(S0, tw[30], c2u_b2, S2, H2, 8, SB, SB);

        // ---- up path level 1 ----
        up2x_k<<<g1(8 * A1), THREADS, 0, stream>>>(S2, S0, 8 * A1, 18, 9, H2, SB, SB);
        conv_k<8, 8, 3, true, 8><<<gp(A1, 8), THREADS, 0, stream>>>(S0, tw[31], up1_b, S0 + 8 * A1, H1, 9, SB, SB);
        copy_k<<<g1(2 * A1), THREADS, 0, stream>>>((float4*)(S0 + 16 * A1), (const float4*)L1,
                                                   2 * A1, SB / 4, SB / 4);
        conv_k<16, 8, 3, true, 8><<<gp(A1, 8), THREADS, 0, stream>>>(S0 + 8 * A1, tw[32], c1u_b1, S1, H1, 9, SB, SB);
        conv_k<8, 2, 3, true, 8><<<gp(A1, 8), THREADS, 0, stream>>>(S1, tw[33], c1u_b2, outp, H1, 9, SB, obs);
    };

    for (int g = 0; g < 4; g += B)
        run_all(B, wsf + TW_FLOATS, SLOT,
                x + (size_t)g * 4 * A1, 4 * A1,
                out + (size_t)g * 2 * A1, 2 * A1);
}

// Round 16
// 1540.824 us; speedup vs baseline: 1.0505x; 1.0505x over previous
//
#include <hip/hip_runtime.h>
#include <math.h>

#define THREADS 256
typedef __attribute__((ext_vector_type(2))) float f32x2;
typedef __attribute__((ext_vector_type(4))) float f32x4;

__device__ __forceinline__ float silu_f(float v) {
    return v / (1.f + __expf(-v));
}

// packed fp32 fma, VGPR weight pair
__device__ __forceinline__ void pk_fma_lo(f32x2& d, f32x2 a, f32x2 b) {
    asm("v_pk_fma_f32 %0, %1, %2, %0 op_sel:[0,0,0] op_sel_hi:[0,1,1]"
        : "+v"(d) : "v"(a), "v"(b));
}
__device__ __forceinline__ void pk_fma_hi(f32x2& d, f32x2 a, f32x2 b) {
    asm("v_pk_fma_f32 %0, %1, %2, %0 op_sel:[1,0,0] op_sel_hi:[1,1,1]"
        : "+v"(d) : "v"(a), "v"(b));
}
// packed fp32 fma, SGPR weight pair (one scalar source legal on VOP3P)
__device__ __forceinline__ void pk_fma_lo_s(f32x2& d, f32x2 a, f32x2 b) {
    asm("v_pk_fma_f32 %0, %1, %2, %0 op_sel:[0,0,0] op_sel_hi:[0,1,1]"
        : "+v"(d) : "v"(a), "s"(b));
}
__device__ __forceinline__ void pk_fma_hi_s(f32x2& d, f32x2 a, f32x2 b) {
    asm("v_pk_fma_f32 %0, %1, %2, %0 op_sel:[1,0,0] op_sel_hi:[1,1,1]"
        : "+v"(d) : "v"(a), "s"(b));
}

// ---------------------------------------------------------------------------
// Weight transpose: [co][ci][k2] -> [ci][k2][co]
// ---------------------------------------------------------------------------
struct TEnt { const float* src; int dst; int cin; int cout; int k2; int base; int n; };
struct TTab { TEnt e[40]; int total; };

__global__ __launch_bounds__(THREADS)
void transpose_w_k(TTab t, float* __restrict__ tw) {
    const int i = blockIdx.x * THREADS + threadIdx.x;
    if (i >= t.total) return;
    int j = 0;
    while (i >= t.e[j].base + t.e[j].n) ++j;
    const TEnt e = t.e[j];
    const int local = i - e.base;
    const int co  = local % e.cout;
    const int tmp = local / e.cout;
    const int k   = tmp % e.k2;
    const int ci  = tmp / e.k2;
    tw[e.dst + local] = e.src[(co * e.cin + ci) * e.k2 + k];
}

// aligned-chunk row loader; interior chunks skip per-lane x checks.
template<int KS, int PX>
__device__ __forceinline__ void load_row(float* __restrict__ rr,
                                         const float* __restrict__ rp,
                                         bool vy, int x0, int W)
{
    constexpr int PAD = (KS - 1) / 2;
    constexpr int RW = PX + KS - 1;
#pragma unroll
    for (int q = -1; q <= PX / 4; ++q) {
        if (4 * q + 3 + PAD < 0 || 4 * q + PAD >= RW) continue;
        const int xs = x0 + 4 * q;
        const bool safe = (q >= 0) && (4 * q + 3 < PX);   // compile-time per q
        float vc[4] = {0.f, 0.f, 0.f, 0.f};
        if (safe) {
            if (vy) {
                const float4 v = *reinterpret_cast<const float4*>(rp + xs);
                vc[0] = v.x; vc[1] = v.y; vc[2] = v.z; vc[3] = v.w;
            }
        } else if (vy && xs >= 0 && xs + 4 <= W) {
            const float4 v = *reinterpret_cast<const float4*>(rp + xs);
            vc[0] = v.x; vc[1] = v.y; vc[2] = v.z; vc[3] = v.w;
        } else if (vy) {
#pragma unroll
            for (int c = 0; c < 4; ++c)
                vc[c] = ((unsigned)(xs + c) < (unsigned)W) ? rp[xs + c] : 0.f;
        }
#pragma unroll
        for (int c = 0; c < 4; ++c) {
            const int t = 4 * q + c + PAD;
            if (t >= 0 && t < RW) rr[t] = vc[c];
        }
    }
}

// ---------------------------------------------------------------------------
// SGPR-weight per-channel body (round-15: wins for BIG convs — many FMAs
// per tap hide s_load latency; round-15 lesson:小 convs regress, keep LDS).
// ---------------------------------------------------------------------------
template<int CIN, int COUT, int KS, int PX, int PHASE, int RW2, int NP>
__device__ __forceinline__ void chan_body(
    const float* __restrict__ ip0, const float* __restrict__ wz,
    int cl, int y, int x0, int W, int H, int lw, int total,
    f32x2 (&r2)[2][RW2], f32x2 (&wb)[2][NP], f32x2 (&acc)[NP][PX])
{
    constexpr int PAD = (KS - 1) / 2;
    constexpr int K2 = KS * KS;
    static_assert(K2 % 2 == 1, "parity continuity needs odd K2");
#pragma unroll
    for (int ky = 0; ky < KS; ++ky) {
        {
            const bool last = (ky + 1 == KS);
            const int ncl = cl + (last ? 1 : 0);
            const int nky = last ? 0 : (ky + 1);
            if (!last || ncl < CIN) {
                const int yy = y + nky - PAD;
                load_row<KS, PX>((float*)r2[(PHASE + ky + 1) & 1],
                                 ip0 + (size_t)ncl * total + (yy << lw),
                                 (unsigned)yy < (unsigned)H, x0, W);
            }
        }
#pragma unroll
        for (int kx = 0; kx < KS; ++kx) {
            const int t = ky * KS + kx;
            const int wc = (PHASE + t) & 1;
            if (t + 1 < K2 || cl + 1 < CIN) {
                const f32x2* __restrict__ nx =
                    (const f32x2*)(wz + (size_t)(cl * K2 + t + 1) * COUT);
#pragma unroll
                for (int p = 0; p < NP; ++p) wb[wc ^ 1][p] = nx[p];
            }
#pragma unroll
            for (int p = 0; p < NP; ++p) {
                const f32x2 wp = wb[wc][p];
#pragma unroll
                for (int j = 0; j < PX; ++j) {
                    const int e = kx + j;
                    if (e & 1) pk_fma_hi_s(acc[p][j], r2[(PHASE + ky) & 1][e >> 1], wp);
                    else       pk_fma_lo_s(acc[p][j], r2[(PHASE + ky) & 1][e >> 1], wp);
                }
            }
            __builtin_amdgcn_sched_barrier(0);
        }
    }
}

// ---------------------------------------------------------------------------
// Sliced direct conv2d (BIG 5x5 convs): 1-D grid, XCD-grouped decode
// (round-14: slices of one (xb,b) group share lin%8 -> same XCD L2).
// SGPR weights -> zero LDS (round-15 win). Round-12: acc <= ~64 f32x2.
// ---------------------------------------------------------------------------
template<int CIN, int COUT, int KS, bool ACT, int PX>
__global__ __launch_bounds__(THREADS)
void conv_sl_k(const float* __restrict__ in, const float* __restrict__ wt,
               const float* __restrict__ bias, float* __restrict__ out,
               int H, int lw, int bs_in, int bs_out, int nb, int nz)
{
    constexpr int PAD = (KS - 1) / 2;
    constexpr int K2 = KS * KS;
    constexpr int NP = COUT / 2;
    constexpr int RW = PX + KS - 1;
    constexpr int RW2 = (RW + 1) / 2;
    static_assert(CIN % 2 == 0 && COUT % 2 == 0 && PX % 4 == 0, "");

    const int lin = blockIdx.x;
    const int r8 = lin & 7;
    int q = lin >> 3;
    const int z = q % nz; q /= nz;
    const int g = q * 8 + r8;
    const int b = g % nb;
    const int xb = g / nb;

    const float* __restrict__ wz = wt + (size_t)z * (CIN * K2 * COUT);
    const int W = 1 << lw;
    const int total = H << lw;
    const int idx = (xb * THREADS + threadIdx.x) * PX;
    const float* ip0 = in + (size_t)b * bs_in;
    float* op = out + (size_t)b * bs_out + (size_t)z * COUT * total;
    const int x0 = idx & (W - 1);
    const int y  = idx >> lw;

    f32x2 acc[NP][PX];
#pragma unroll
    for (int p = 0; p < NP; ++p) {
        f32x2 bb;
        bb.x = bias[z * COUT + 2 * p];
        bb.y = bias[z * COUT + 2 * p + 1];
#pragma unroll
        for (int j = 0; j < PX; ++j) acc[p][j] = bb;
    }

    f32x2 r2[2][RW2];
    f32x2 wb[2][NP];
    {
        const int yy = y - PAD;
        load_row<KS, PX>((float*)r2[0], ip0 + (yy << lw),
                         (unsigned)yy < (unsigned)H, x0, W);
        const f32x2* __restrict__ w0 = (const f32x2*)wz;
#pragma unroll
        for (int p = 0; p < NP; ++p) wb[0][p] = w0[p];
    }

#pragma unroll 1
    for (int c2 = 0; c2 < CIN / 2; ++c2) {
        chan_body<CIN, COUT, KS, PX, 0, RW2, NP>(ip0, wz, 2 * c2,     y, x0, W, H, lw, total, r2, wb, acc);
        chan_body<CIN, COUT, KS, PX, 1, RW2, NP>(ip0, wz, 2 * c2 + 1, y, x0, W, H, lw, total, r2, wb, acc);
    }

#pragma unroll
    for (int p = 0; p < NP; ++p) {
#pragma unroll
        for (int h = 0; h < 2; ++h) {
            const int co = 2 * p + h;
#pragma unroll
            for (int j4 = 0; j4 < PX / 4; ++j4) {
                float4 v;
                float a0 = h ? acc[p][4 * j4 + 0].y : acc[p][4 * j4 + 0].x;
                float a1 = h ? acc[p][4 * j4 + 1].y : acc[p][4 * j4 + 1].x;
                float a2 = h ? acc[p][4 * j4 + 2].y : acc[p][4 * j4 + 2].x;
                float a3 = h ? acc[p][4 * j4 + 3].y : acc[p][4 * j4 + 3].x;
                v.x = ACT ? silu_f(a0) : a0;
                v.y = ACT ? silu_f(a1) : a1;
                v.z = ACT ? silu_f(a2) : a2;
                v.w = ACT ? silu_f(a3) : a3;
                *reinterpret_cast<float4*>(op + (size_t)co * total + idx + 4 * j4) = v;
            }
        }
    }
}

// ---------------------------------------------------------------------------
// Generic direct conv2d (SMALL convs): LDS weights, b128 broadcast (round-14
// variant — measured better than SGPR weights when FMA/tap is small).
// ---------------------------------------------------------------------------
template<int CIN, int COUT, int KS, bool ACT, int PX>
__global__ __launch_bounds__(THREADS)
void conv_k(const float* __restrict__ in, const float* __restrict__ wt,
            const float* __restrict__ bias, float* __restrict__ out,
            int H, int lw, int bs_in, int bs_out)
{
    constexpr int PAD = (KS - 1) / 2;
    constexpr int K2 = KS * KS;
    constexpr int CO_S = (COUT + 3) & ~3;
    constexpr int WQ = CO_S / 4;
    constexpr int NP = COUT / 2;
    constexpr int RW = PX + KS - 1;
    constexpr int RW2 = (RW + 1) / 2;
    static_assert(COUT % 2 == 0, "");
    __shared__ float sw[CIN * K2 * CO_S];

    const int W = 1 << lw;
    const int total = H << lw;
    const int idx = (blockIdx.x * THREADS + threadIdx.x) * PX;
    const float* ip0 = in + (size_t)blockIdx.y * bs_in;
    float* op = out + (size_t)blockIdx.y * bs_out;
    const int x0 = idx & (W - 1);
    const int y  = idx >> lw;

    for (int i = threadIdx.x; i < CIN * K2 * COUT; i += THREADS)
        sw[(i / COUT) * CO_S + i % COUT] = wt[i];
    __syncthreads();

    f32x2 acc[NP][PX];
#pragma unroll
    for (int p = 0; p < NP; ++p) {
        f32x2 bb;
        bb.x = bias[2 * p];
        bb.y = bias[2 * p + 1];
#pragma unroll
        for (int j = 0; j < PX; ++j) acc[p][j] = bb;
    }

#pragma unroll 1
    for (int cl = 0; cl < CIN; ++cl) {
        const float* __restrict__ row0 = ip0 + (size_t)cl * total;
        f32x2 r2[KS][RW2];
#pragma unroll
        for (int ky = 0; ky < KS; ++ky) {
            const int yy = y + ky - PAD;
            load_row<KS, PX>((float*)r2[ky], row0 + (yy << lw),
                             (unsigned)yy < (unsigned)H, x0, W);
        }
        const float* __restrict__ wbase = &sw[cl * K2 * CO_S];
#pragma unroll
        for (int t = 0; t < K2; ++t) {
            const int ky = t / KS, kx = t % KS;
            const f32x4* __restrict__ wv = (const f32x4*)(wbase + t * CO_S);
#pragma unroll
            for (int q = 0; q < WQ; ++q) {
                const f32x4 w4 = wv[q];
                const f32x2 wlo = __builtin_shufflevector(w4, w4, 0, 1);
                const f32x2 whi = __builtin_shufflevector(w4, w4, 2, 3);
#pragma unroll
                for (int s = 0; s < 2; ++s) {
                    const int p = 2 * q + s;
                    if (p < NP) {
                        const f32x2 wp = s ? whi : wlo;
#pragma unroll
                        for (int j = 0; j < PX; ++j) {
                            const int e = kx + j;
                            if (e & 1) pk_fma_hi(acc[p][j], r2[ky][e >> 1], wp);
                            else       pk_fma_lo(acc[p][j], r2[ky][e >> 1], wp);
                        }
                    }
                }
            }
            __builtin_amdgcn_sched_barrier(0);
        }
    }

#pragma unroll
    for (int p = 0; p < NP; ++p) {
#pragma unroll
        for (int h = 0; h < 2; ++h) {
            const int co = 2 * p + h;
            if (PX == 2) {
                float2 v;
                float a0 = h ? acc[p][0].y : acc[p][0].x;
                float a1 = h ? acc[p][1].y : acc[p][1].x;
                v.x = ACT ? silu_f(a0) : a0;
                v.y = ACT ? silu_f(a1) : a1;
                *reinterpret_cast<float2*>(op + (size_t)co * total + idx) = v;
            } else {
#pragma unroll
                for (int j4 = 0; j4 < PX / 4; ++j4) {
                    float4 v;
                    float a0 = h ? acc[p][4 * j4 + 0].y : acc[p][4 * j4 + 0].x;
                    float a1 = h ? acc[p][4 * j4 + 1].y : acc[p][4 * j4 + 1].x;
                    float a2 = h ? acc[p][4 * j4 + 2].y : acc[p][4 * j4 + 2].x;
                    float a3 = h ? acc[p][4 * j4 + 3].y : acc[p][4 * j4 + 3].x;
                    v.x = ACT ? silu_f(a0) : a0;
                    v.y = ACT ? silu_f(a1) : a1;
                    v.z = ACT ? silu_f(a2) : a2;
                    v.w = ACT ? silu_f(a3) : a3;
                    *reinterpret_cast<float4*>(op + (size_t)co * total + idx + 4 * j4) = v;
                }
            }
        }
    }
}

// ---------------------------------------------------------------------------
// DeformConv2d: 3x3, stride 1, pad 1, no bias. groups=2, offset groups=2.
// ---------------------------------------------------------------------------
template<int CIN, int COUT>
__global__ __launch_bounds__(THREADS)
void dconv_k(const float* __restrict__ in, const float* __restrict__ off,
             const float* __restrict__ twg0, const float* __restrict__ twg1,
             float* __restrict__ out,
             int H, int lw, int bs_in, int bs_off, int bs_out)
{
    constexpr int K = 9;
    constexpr int OG = 2;
    constexpr int COG = CIN / OG;
    constexpr int COUTG = COUT / 2;
    constexpr int NWG = COG * K * COUTG;
    __shared__ float sw[2 * NWG];
    for (int i = threadIdx.x; i < 2 * NWG; i += THREADS)
        sw[i] = (i < NWG) ? twg0[i] : twg1[i - NWG];
    __syncthreads();

    const int W = 1 << lw;
    const int total = H << lw;
    const int idx = blockIdx.x * THREADS + threadIdx.x;
    const float* ip0 = in + (size_t)blockIdx.y * bs_in;
    const float* offp = off + (size_t)blockIdx.y * bs_off;
    float* op = out + (size_t)blockIdx.y * bs_out;
    const int x = idx & (W - 1);
    const int y = idx >> lw;

    float acc[COUT];
#pragma unroll
    for (int co = 0; co < COUT; ++co) acc[co] = 0.f;

#pragma unroll
    for (int og = 0; og < OG; ++og) {
#pragma unroll
        for (int k = 0; k < K; ++k) {
            const int ki = k / 3 - 1;
            const int kj = k % 3 - 1;
            const float dy = offp[(size_t)(((og * K + k) * 2 + 0)) * total + idx];
            const float dx = offp[(size_t)(((og * K + k) * 2 + 1)) * total + idx];
            const float py = dy + (float)(y + ki);
            const float px = dx + (float)(x + kj);
            const float y0f = floorf(py), x0f = floorf(px);
            const float ly = py - y0f, lx = px - x0f;
            const int y0 = (int)y0f, x0 = (int)x0f;
            const int y1 = y0 + 1, x1 = x0 + 1;
            const bool vy0 = (unsigned)y0 < (unsigned)H;
            const bool vy1 = (unsigned)y1 < (unsigned)H;
            const bool vx0 = (unsigned)x0 < (unsigned)W;
            const bool vx1 = (unsigned)x1 < (unsigned)W;
            const int cy0 = min(max(y0, 0), H - 1), cy1 = min(max(y1, 0), H - 1);
            const int cx0 = min(max(x0, 0), W - 1), cx1 = min(max(x1, 0), W - 1);
            const int i00 = (cy0 << lw) + cx0, i01 = (cy0 << lw) + cx1;
            const int i10 = (cy1 << lw) + cx0, i11 = (cy1 << lw) + cx1;
            const float f00 = (vy0 && vx0) ? (1.f - ly) * (1.f - lx) : 0.f;
            const float f01 = (vy0 && vx1) ? (1.f - ly) * lx : 0.f;
            const float f10 = (vy1 && vx0) ? ly * (1.f - lx) : 0.f;
            const float f11 = (vy1 && vx1) ? ly * lx : 0.f;
            const float* swg = &sw[og * NWG];
#pragma unroll
            for (int c = 0; c < COG; ++c) {
                const float* __restrict__ ip = ip0 + (size_t)(og * COG + c) * total;
                const float v = f00 * ip[i00] + f01 * ip[i01]
                              + f10 * ip[i10] + f11 * ip[i11];
                const float* __restrict__ wr = &swg[(c * K + k) * COUTG];
#pragma unroll
                for (int col = 0; col < COUTG; ++col)
                    acc[og * COUTG + col] = fmaf(v, wr[col], acc[og * COUTG + col]);
            }
        }
    }

#pragma unroll
    for (int co = 0; co < COUT; ++co)
        op[(size_t)co * total + idx] = acc[co];
}

// 2x2 average pool.
__global__ __launch_bounds__(THREADS)
void avgpool_k(const float* __restrict__ in, float* __restrict__ out,
               int n, int lt, int lwo, int bsi, int bso)
{
    const int idx = blockIdx.x * THREADS + threadIdx.x;
    if (idx >= n) return;
    const float* ip0 = in + (size_t)blockIdx.y * bsi;
    float* op = out + (size_t)blockIdx.y * bso;
    const int c = idx >> lt;
    const int r = idx & ((1 << lt) - 1);
    const int oy = r >> lwo;
    const int ox = r & ((1 << lwo) - 1);
    const int Wi = 2 << lwo;
    const float* ip = ip0 + ((size_t)c << (lt + 2)) + ((size_t)(2 * oy) << (lwo + 1)) + 2 * ox;
    const float2 t = *reinterpret_cast<const float2*>(ip);
    const float2 b = *reinterpret_cast<const float2*>(ip + Wi);
    op[idx] = 0.25f * (t.x + t.y + b.x + b.y);
}

// Bilinear 2x upsample, align_corners=True.
__global__ __launch_bounds__(THREADS)
void up2x_k(const float* __restrict__ in, float* __restrict__ out,
            int n, int lt, int lwo, int Hin, int bsi, int bso)
{
    const int idx = blockIdx.x * THREADS + threadIdx.x;
    if (idx >= n) return;
    const float* ip0 = in + (size_t)blockIdx.y * bsi;
    float* op = out + (size_t)blockIdx.y * bso;
    const int c = idx >> lt;
    const int r = idx & ((1 << lt) - 1);
    const int oy = r >> lwo;
    const int ox = r & ((1 << lwo) - 1);
    const int W = 1 << (lwo - 1);
    const int H = Hin;
    const float s = (float)(H - 1) / (float)(2 * H - 1);
    const float fy = (float)oy * s;
    const float fx = (float)ox * s;
    const int y0 = (int)fy;
    const int x0 = (int)fx;
    const int y1 = min(y0 + 1, H - 1);
    const int x1 = min(x0 + 1, W - 1);
    const float wy = fy - (float)y0;
    const float wx = fx - (float)x0;
    const float* ip = ip0 + ((size_t)c << (lt - 2));
    const float v00 = ip[y0 * W + x0], v01 = ip[y0 * W + x1];
    const float v10 = ip[y1 * W + x0], v11 = ip[y1 * W + x1];
    op[idx] = (v00 * (1.f - wy) + v10 * wy) * (1.f - wx)
            + (v01 * (1.f - wy) + v11 * wy) * wx;
}

// strided batched d2d copy (float4 granularity)
__global__ __launch_bounds__(THREADS)
void copy_k(float4* __restrict__ dst, const float4* __restrict__ src,
            int n4, int bsd, int bss)
{
    const int i = blockIdx.x * THREADS + threadIdx.x;
    if (i >= n4) return;
    dst[(size_t)blockIdx.y * bsd + i] = src[(size_t)blockIdx.y * bss + i];
}

// ---------------------------------------------------------------------------

extern "C" void kernel_launch(void* const* d_in, const int* in_sizes, int n_in,
                              void* d_out, int out_size, void* d_ws, size_t ws_size,
                              hipStream_t stream) {
    const float* x      = (const float*)d_in[0];
    const float* eo1_b1 = (const float*)d_in[2];
    const float* eo1_b2 = (const float*)d_in[4];
    const float* c1d_b1 = (const float*)d_in[7];
    const float* c1d_b2 = (const float*)d_in[9];
    const float* eo2_b1 = (const float*)d_in[11];
    const float* eo2_b2 = (const float*)d_in[13];
    const float* c2d_b1 = (const float*)d_in[16];
    const float* c2d_b2 = (const float*)d_in[18];
    const float* eo3_b1 = (const float*)d_in[20];
    const float* eo3_b2 = (const float*)d_in[22];
    const float* c3d_b1 = (const float*)d_in[25];
    const float* c3d_b2 = (const float*)d_in[27];
    const float* up2_b  = (const float*)d_in[29];
    const float* c2u_b1 = (const float*)d_in[31];
    const float* c2u_b2 = (const float*)d_in[33];
    const float* up1_b  = (const float*)d_in[35];
    const float* c1u_b1 = (const float*)d_in[37];
    const float* c1u_b2 = (const float*)d_in[39];

    float* out = (float*)d_out;
    float* wsf = (float*)d_ws;

    constexpr int H1 = 512, A1 = H1 * H1;
    constexpr int H2 = 256, A2 = H2 * H2;
    constexpr int H3 = 128, A3 = H3 * H3;
    constexpr int TW_FLOATS = 81920;
    constexpr int SLOT = 58 * A1;

    // ---- transposed-weight table (round-11 shape): 34 conv + 6 dconv ----
    const int widx[34]  = {1, 1, 1,  3, 3, 3, 3, 3,  6, 8,
                           10, 10, 10,  12, 12, 12, 12, 12,  15, 17,
                           19,  21, 21, 21, 21, 21,  24, 26,
                           28, 30, 32, 34, 36, 38};
    const int wcin[34]  = {4, 4, 4,  18, 18, 18, 18, 18,  2, 4,
                           8, 8, 8,  18, 18, 18, 18, 18,  8, 12,
                           16,  18, 18, 18, 18, 18,  16, 14,
                           12, 28, 16, 8, 16, 8};
    const int wcout[34] = {6, 6, 6,  8, 8, 8, 8, 4,  4, 8,
                           6, 6, 6,  8, 8, 8, 8, 4,  12, 16,
                           18,  8, 8, 8, 8, 4,  14, 12,
                           12, 16, 8, 8, 8, 2};
    const int wk2[34]   = {25, 25, 25,  25, 25, 25, 25, 25,  9, 9,
                           25, 25, 25,  25, 25, 25, 25, 25,  9, 9,
                           25,  25, 25, 25, 25, 25,  9, 9,
                           9, 9, 9, 9, 9, 9};
    const int wsoff[34] = {0, 600, 1200,  0, 3600, 7200, 10800, 14400,  0, 0,
                           0, 1200, 2400,  0, 3600, 7200, 10800, 14400,  0, 0,
                           0,  0, 3600, 7200, 10800, 14400,  0, 0,
                           0, 0, 0, 0, 0, 0};
    const int cont[34]  = {1, 1, 0,  1, 1, 1, 0, 0,  0, 0,
                           1, 1, 0,  1, 1, 1, 0, 0,  0, 0,
                           0,  1, 1, 1, 0, 0,  0, 0,
                           0, 0, 0, 0, 0, 0};
    TTab tab;
    const float* tw[40];
    int off = 0, base = 0;
    for (int i = 0; i < 34; ++i) {
        const int n = wcin[i] * wcout[i] * wk2[i];
        tab.e[i].src = (const float*)d_in[widx[i]] + wsoff[i];
        tab.e[i].dst = off; tab.e[i].cin = wcin[i]; tab.e[i].cout = wcout[i];
        tab.e[i].k2 = wk2[i]; tab.e[i].base = base; tab.e[i].n = n;
        tw[i] = wsf + off;
        off = cont[i] ? (off + n) : ((off + n + 63) & ~63);
        base += n;
    }
    const int didx[3]   = {5, 14, 23};
    const int dcoutg[3] = {1, 4, 8};
    const int dcpg[3]   = {2, 4, 8};
    for (int i = 0; i < 3; ++i) {
        for (int g = 0; g < 2; ++g) {
            const int e = 34 + 2 * i + g;
            const int n = dcoutg[i] * dcpg[i] * 9;
            tab.e[e].src = (const float*)d_in[didx[i]] + (size_t)g * n;
            tab.e[e].dst = off; tab.e[e].cin = dcpg[i]; tab.e[e].cout = dcoutg[i];
            tab.e[e].k2 = 9; tab.e[e].base = base; tab.e[e].n = n;
            tw[e] = wsf + off;
            off = (off + n + 63) & ~63;
            base += n;
        }
    }
    tab.total = base;
    transpose_w_k<<<(base + THREADS - 1) / THREADS, THREADS, 0, stream>>>(tab, wsf);

    int B = 4;
    while (B > 1 && ws_size < ((size_t)TW_FLOATS + (size_t)B * SLOT) * sizeof(float)) B >>= 1;

    auto run_all = [&](int Bc, float* slot, int SB,
                       const float* xin, int xbs, float* outp, int obs) {
        float* S0 = slot;
        float* S1 = S0 + 36 * A1;
        float* S2 = S1 + 18 * A1;
        float* P  = S2 + 2 * A1;
        float* L1 = S1 + 10 * A1;
        float* L2 = S0 + 32 * A1;
        auto gs = [&](int n, int px, int z) { return dim3((n / (px * THREADS)) * Bc * z); };
        auto gp = [&](int n, int px) { return dim3(n / (px * THREADS), Bc); };
        auto g1 = [&](int n) { return dim3((n + THREADS - 1) / THREADS, Bc); };

        // ---- level 1 down ----
        conv_sl_k<4, 6, 5, false, 8><<<gs(A1, 8, 3), THREADS, 0, stream>>>(xin, tw[0], eo1_b1, S1, H1, 9, xbs, SB, Bc, 3);
        conv_sl_k<18, 8, 5, false, 8><<<gs(A1, 8, 4), THREADS, 0, stream>>>(S1, tw[3], eo1_b2, S0, H1, 9, SB, SB, Bc, 4);
        conv_sl_k<18, 4, 5, false, 8><<<gs(A1, 8, 1), THREADS, 0, stream>>>(S1, tw[7], eo1_b2 + 32, S0 + 32 * A1, H1, 9, SB, SB, Bc, 1);
        dconv_k<4, 2><<<g1(A1), THREADS, 0, stream>>>(xin, S0, tw[34], tw[35], S2, H1, 9, xbs, SB, SB);
        conv_k<2, 4, 3, true, 8><<<gp(A1, 8), THREADS, 0, stream>>>(S2, tw[8], c1d_b1, S1, H1, 9, SB, SB);
        conv_k<4, 8, 3, true, 8><<<gp(A1, 8), THREADS, 0, stream>>>(S1, tw[9], c1d_b2, L1, H1, 9, SB, SB);
        avgpool_k<<<g1(8 * A2), THREADS, 0, stream>>>(L1, P, 8 * A2, 16, 8, SB, SB);

        // ---- level 2 down ----
        conv_sl_k<8, 6, 5, false, 8><<<gs(A2, 8, 3), THREADS, 0, stream>>>(P, tw[10], eo2_b1, S1, H2, 8, SB, SB, Bc, 3);
        conv_sl_k<18, 8, 5, false, 8><<<gs(A2, 8, 4), THREADS, 0, stream>>>(S1, tw[13], eo2_b2, S0, H2, 8, SB, SB, Bc, 4);
        conv_sl_k<18, 4, 5, false, 8><<<gs(A2, 8, 1), THREADS, 0, stream>>>(S1, tw[17], eo2_b2 + 32, S0 + 32 * A2, H2, 8, SB, SB, Bc, 1);
        dconv_k<8, 8><<<g1(A2), THREADS, 0, stream>>>(P, S0, tw[36], tw[37], S2, H2, 8, SB, SB, SB);
        conv_k<8, 12, 3, true, 4><<<gp(A2, 4), THREADS, 0, stream>>>(S2, tw[18], c2d_b1, S1, H2, 8, SB, SB);
        conv_k<12, 16, 3, true, 4><<<gp(A2, 4), THREADS, 0, stream>>>(S1, tw[19], c2d_b2, L2, H2, 8, SB, SB);
        avgpool_k<<<g1(16 * A3), THREADS, 0, stream>>>(L2, P, 16 * A3, 14, 7, SB, SB);

        // ---- level 3 (bottleneck) ----
        conv_k<16, 18, 5, false, 2><<<gp(A3, 2), THREADS, 0, stream>>>(P, tw[20], eo3_b1, S1, H3, 7, SB, SB);
        conv_sl_k<18, 8, 5, false, 4><<<gs(A3, 4, 4), THREADS, 0, stream>>>(S1, tw[21], eo3_b2, S0, H3, 7, SB, SB, Bc, 4);
        conv_sl_k<18, 4, 5, false, 4><<<gs(A3, 4, 1), THREADS, 0, stream>>>(S1, tw[25], eo3_b2 + 32, S0 + 32 * A3, H3, 7, SB, SB, Bc, 1);
        dconv_k<16, 16><<<g1(A3), THREADS, 0, stream>>>(P, S0, tw[38], tw[39], S2, H3, 7, SB, SB, SB);
        conv_k<16, 14, 3, true, 2><<<gp(A3, 2), THREADS, 0, stream>>>(S2, tw[26], c3d_b1, S1, H3, 7, SB, SB);
        conv_k<14, 12, 3, true, 2><<<gp(A3, 2), THREADS, 0, stream>>>(S1, tw[27], c3d_b2, S2, H3, 7, SB, SB);

        // ---- up path level 2 ----
        up2x_k<<<g1(12 * A2), THREADS, 0, stream>>>(S2, S0, 12 * A2, 16, 8, H3, SB, SB);
        conv_k<12, 12, 3, true, 4><<<gp(A2, 4), THREADS, 0, stream>>>(S0, tw[28], up2_b, S1, H2, 8, SB, SB);
        copy_k<<<g1(4 * A2), THREADS, 0, stream>>>((float4*)(S1 + 12 * A2), (const float4*)L2,
                                                   4 * A2, SB / 4, SB / 4);
        conv_k<28, 16, 3, true, 4><<<gp(A2, 4), THREADS, 0, stream>>>(S1, tw[29], c2u_b1, S0, H2, 8, SB, SB);
        conv_k<16, 8, 3, true, 4><<<gp(A2, 4), THREADS, 0, stream>>>(S0, tw[30], c2u_b2, S2, H2, 8, SB, SB);

        // ---- up path level 1 ----
        up2x_k<<<g1(8 * A1), THREADS, 0, stream>>>(S2, S0, 8 * A1, 18, 9, H2, SB, SB);
        conv_k<8, 8, 3, true, 8><<<gp(A1, 8), THREADS, 0, stream>>>(S0, tw[31], up1_b, S0 + 8 * A1, H1, 9, SB, SB);
        copy_k<<<g1(2 * A1), THREADS, 0, stream>>>((float4*)(S0 + 16 * A1), (const float4*)L1,
                                                   2 * A1, SB / 4, SB / 4);
        conv_k<16, 8, 3, true, 8><<<gp(A1, 8), THREADS, 0, stream>>>(S0 + 8 * A1, tw[32], c1u_b1, S1, H1, 9, SB, SB);
        conv_k<8, 2, 3, true, 8><<<gp(A1, 8), THREADS, 0, stream>>>(S1, tw[33], c1u_b2, outp, H1, 9, SB, obs);
    };

    for (int g = 0; g < 4; g += B)
        run_all(B, wsf + TW_FLOATS, SLOT,
                x + (size_t)g * 4 * A1, 4 * A1,
                out + (size_t)g * 2 * A1, 2 * A1);
}

// Round 17
// 1404.416 us; speedup vs baseline: 1.1525x; 1.0971x over previous
//
#include <hip/hip_runtime.h>
#include <math.h>

#define THREADS 256
typedef __attribute__((ext_vector_type(2))) float f32x2;
typedef __attribute__((ext_vector_type(4))) float f32x4;

__device__ __forceinline__ float silu_f(float v) {
    return v / (1.f + __expf(-v));
}

// packed fp32 fma, VGPR weight pair
__device__ __forceinline__ void pk_fma_lo(f32x2& d, f32x2 a, f32x2 b) {
    asm("v_pk_fma_f32 %0, %1, %2, %0 op_sel:[0,0,0] op_sel_hi:[0,1,1]"
        : "+v"(d) : "v"(a), "v"(b));
}
__device__ __forceinline__ void pk_fma_hi(f32x2& d, f32x2 a, f32x2 b) {
    asm("v_pk_fma_f32 %0, %1, %2, %0 op_sel:[1,0,0] op_sel_hi:[1,1,1]"
        : "+v"(d) : "v"(a), "v"(b));
}
// packed fp32 fma, SGPR weight pair (one scalar source legal on VOP3P)
__device__ __forceinline__ void pk_fma_lo_s(f32x2& d, f32x2 a, f32x2 b) {
    asm("v_pk_fma_f32 %0, %1, %2, %0 op_sel:[0,0,0] op_sel_hi:[0,1,1]"
        : "+v"(d) : "v"(a), "s"(b));
}
__device__ __forceinline__ void pk_fma_hi_s(f32x2& d, f32x2 a, f32x2 b) {
    asm("v_pk_fma_f32 %0, %1, %2, %0 op_sel:[1,0,0] op_sel_hi:[1,1,1]"
        : "+v"(d) : "v"(a), "s"(b));
}

// ---------------------------------------------------------------------------
// Weight transpose: [co][ci][k2] -> [ci][k2][co]
// ---------------------------------------------------------------------------
struct TEnt { const float* src; int dst; int cin; int cout; int k2; int base; int n; };
struct TTab { TEnt e[40]; int total; };

__global__ __launch_bounds__(THREADS)
void transpose_w_k(TTab t, float* __restrict__ tw) {
    const int i = blockIdx.x * THREADS + threadIdx.x;
    if (i >= t.total) return;
    int j = 0;
    while (i >= t.e[j].base + t.e[j].n) ++j;
    const TEnt e = t.e[j];
    const int local = i - e.base;
    const int co  = local % e.cout;
    const int tmp = local / e.cout;
    const int k   = tmp % e.k2;
    const int ci  = tmp / e.k2;
    tw[e.dst + local] = e.src[(co * e.cin + ci) * e.k2 + k];
}

// aligned-chunk row loader; interior chunks skip per-lane x checks.
template<int KS, int PX>
__device__ __forceinline__ void load_row(float* __restrict__ rr,
                                         const float* __restrict__ rp,
                                         bool vy, int x0, int W)
{
    constexpr int PAD = (KS - 1) / 2;
    constexpr int RW = PX + KS - 1;
#pragma unroll
    for (int q = -1; q <= PX / 4; ++q) {
        if (4 * q + 3 + PAD < 0 || 4 * q + PAD >= RW) continue;
        const int xs = x0 + 4 * q;
        const bool safe = (q >= 0) && (4 * q + 3 < PX);
        float vc[4] = {0.f, 0.f, 0.f, 0.f};
        if (safe) {
            if (vy) {
                const float4 v = *reinterpret_cast<const float4*>(rp + xs);
                vc[0] = v.x; vc[1] = v.y; vc[2] = v.z; vc[3] = v.w;
            }
        } else if (vy && xs >= 0 && xs + 4 <= W) {
            const float4 v = *reinterpret_cast<const float4*>(rp + xs);
            vc[0] = v.x; vc[1] = v.y; vc[2] = v.z; vc[3] = v.w;
        } else if (vy) {
#pragma unroll
            for (int c = 0; c < 4; ++c)
                vc[c] = ((unsigned)(xs + c) < (unsigned)W) ? rp[xs + c] : 0.f;
        }
#pragma unroll
        for (int c = 0; c < 4; ++c) {
            const int t = 4 * q + c + PAD;
            if (t >= 0 && t < RW) rr[t] = vc[c];
        }
    }
}

// ---------------------------------------------------------------------------
// SGPR-weight per-channel body (round-15 win for big convs).
// ---------------------------------------------------------------------------
template<int CIN, int COUT, int KS, int PX, int PHASE, int RW2, int NP>
__device__ __forceinline__ void chan_body(
    const float* __restrict__ ip0, const float* __restrict__ wz,
    int cl, int y, int x0, int W, int H, int lw, int total,
    f32x2 (&r2)[2][RW2], f32x2 (&wb)[2][NP], f32x2 (&acc)[NP][PX])
{
    constexpr int PAD = (KS - 1) / 2;
    constexpr int K2 = KS * KS;
    static_assert(K2 % 2 == 1, "parity continuity needs odd K2");
#pragma unroll
    for (int ky = 0; ky < KS; ++ky) {
        {
            const bool last = (ky + 1 == KS);
            const int ncl = cl + (last ? 1 : 0);
            const int nky = last ? 0 : (ky + 1);
            if (!last || ncl < CIN) {
                const int yy = y + nky - PAD;
                load_row<KS, PX>((float*)r2[(PHASE + ky + 1) & 1],
                                 ip0 + (size_t)ncl * total + (yy << lw),
                                 (unsigned)yy < (unsigned)H, x0, W);
            }
        }
#pragma unroll
        for (int kx = 0; kx < KS; ++kx) {
            const int t = ky * KS + kx;
            const int wc = (PHASE + t) & 1;
            if (t + 1 < K2 || cl + 1 < CIN) {
                const f32x2* __restrict__ nx =
                    (const f32x2*)(wz + (size_t)(cl * K2 + t + 1) * COUT);
#pragma unroll
                for (int p = 0; p < NP; ++p) wb[wc ^ 1][p] = nx[p];
            }
#pragma unroll
            for (int p = 0; p < NP; ++p) {
                const f32x2 wp = wb[wc][p];
#pragma unroll
                for (int j = 0; j < PX; ++j) {
                    const int e = kx + j;
                    if (e & 1) pk_fma_hi_s(acc[p][j], r2[(PHASE + ky) & 1][e >> 1], wp);
                    else       pk_fma_lo_s(acc[p][j], r2[(PHASE + ky) & 1][e >> 1], wp);
                }
            }
            __builtin_amdgcn_sched_barrier(0);
        }
    }
}

// ---------------------------------------------------------------------------
// Sliced direct conv2d (BIG 5x5 convs), SGPR weights, XCD-grouped 1-D grid.
// Round-17: CO12 slices (nz 5->3) cut per-pixel row-load work 40%.
// ---------------------------------------------------------------------------
template<int CIN, int COUT, int KS, bool ACT, int PX>
__global__ __launch_bounds__(THREADS)
void conv_sl_k(const float* __restrict__ in, const float* __restrict__ wt,
               const float* __restrict__ bias, float* __restrict__ out,
               int H, int lw, int bs_in, int bs_out, int nb, int nz)
{
    constexpr int PAD = (KS - 1) / 2;
    constexpr int K2 = KS * KS;
    constexpr int NP = COUT / 2;
    constexpr int RW = PX + KS - 1;
    constexpr int RW2 = (RW + 1) / 2;
    static_assert(CIN % 2 == 0 && COUT % 2 == 0 && PX % 4 == 0, "");

    const int lin = blockIdx.x;
    const int r8 = lin & 7;
    int q = lin >> 3;
    const int z = q % nz; q /= nz;
    const int g = q * 8 + r8;
    const int b = g % nb;
    const int xb = g / nb;

    const float* __restrict__ wz = wt + (size_t)z * (CIN * K2 * COUT);
    const int W = 1 << lw;
    const int total = H << lw;
    const int idx = (xb * THREADS + threadIdx.x) * PX;
    const float* ip0 = in + (size_t)b * bs_in;
    float* op = out + (size_t)b * bs_out + (size_t)z * COUT * total;
    const int x0 = idx & (W - 1);
    const int y  = idx >> lw;

    f32x2 acc[NP][PX];
#pragma unroll
    for (int p = 0; p < NP; ++p) {
        f32x2 bb;
        bb.x = bias[z * COUT + 2 * p];
        bb.y = bias[z * COUT + 2 * p + 1];
#pragma unroll
        for (int j = 0; j < PX; ++j) acc[p][j] = bb;
    }

    f32x2 r2[2][RW2];
    f32x2 wb[2][NP];
    {
        const int yy = y - PAD;
        load_row<KS, PX>((float*)r2[0], ip0 + (yy << lw),
                         (unsigned)yy < (unsigned)H, x0, W);
        const f32x2* __restrict__ w0 = (const f32x2*)wz;
#pragma unroll
        for (int p = 0; p < NP; ++p) wb[0][p] = w0[p];
    }

#pragma unroll 1
    for (int c2 = 0; c2 < CIN / 2; ++c2) {
        chan_body<CIN, COUT, KS, PX, 0, RW2, NP>(ip0, wz, 2 * c2,     y, x0, W, H, lw, total, r2, wb, acc);
        chan_body<CIN, COUT, KS, PX, 1, RW2, NP>(ip0, wz, 2 * c2 + 1, y, x0, W, H, lw, total, r2, wb, acc);
    }

#pragma unroll
    for (int p = 0; p < NP; ++p) {
#pragma unroll
        for (int h = 0; h < 2; ++h) {
            const int co = 2 * p + h;
#pragma unroll
            for (int j4 = 0; j4 < PX / 4; ++j4) {
                float4 v;
                float a0 = h ? acc[p][4 * j4 + 0].y : acc[p][4 * j4 + 0].x;
                float a1 = h ? acc[p][4 * j4 + 1].y : acc[p][4 * j4 + 1].x;
                float a2 = h ? acc[p][4 * j4 + 2].y : acc[p][4 * j4 + 2].x;
                float a3 = h ? acc[p][4 * j4 + 3].y : acc[p][4 * j4 + 3].x;
                v.x = ACT ? silu_f(a0) : a0;
                v.y = ACT ? silu_f(a1) : a1;
                v.z = ACT ? silu_f(a2) : a2;
                v.w = ACT ? silu_f(a3) : a3;
                *reinterpret_cast<float4*>(op + (size_t)co * total + idx + 4 * j4) = v;
            }
        }
    }
}

// ---------------------------------------------------------------------------
// Shared LDS-weight tap sweep for the small convs.
// ---------------------------------------------------------------------------
template<int COUT, int KS, int PX, int WQ, int NP, int RW2>
__device__ __forceinline__ void lds_taps(
    const float* __restrict__ wbase, f32x2 (&r2)[KS][RW2], f32x2 (&acc)[NP][PX])
{
    constexpr int K2 = KS * KS;
    constexpr int CO_S = (COUT + 3) & ~3;
#pragma unroll
    for (int t = 0; t < K2; ++t) {
        const int ky = t / KS, kx = t % KS;
        const f32x4* __restrict__ wv = (const f32x4*)(wbase + t * CO_S);
#pragma unroll
        for (int q = 0; q < WQ; ++q) {
            const f32x4 w4 = wv[q];
            const f32x2 wlo = __builtin_shufflevector(w4, w4, 0, 1);
            const f32x2 whi = __builtin_shufflevector(w4, w4, 2, 3);
#pragma unroll
            for (int s = 0; s < 2; ++s) {
                const int p = 2 * q + s;
                if (p < NP) {
                    const f32x2 wp = s ? whi : wlo;
#pragma unroll
                    for (int j = 0; j < PX; ++j) {
                        const int e = kx + j;
                        if (e & 1) pk_fma_hi(acc[p][j], r2[ky][e >> 1], wp);
                        else       pk_fma_lo(acc[p][j], r2[ky][e >> 1], wp);
                    }
                }
            }
        }
        __builtin_amdgcn_sched_barrier(0);
    }
}

template<int COUT, int PX, bool ACT, int NP>
__device__ __forceinline__ void conv_store(
    float* __restrict__ op, int total, int idx, f32x2 (&acc)[NP][PX])
{
#pragma unroll
    for (int p = 0; p < NP; ++p) {
#pragma unroll
        for (int h = 0; h < 2; ++h) {
            const int co = 2 * p + h;
            if (PX == 2) {
                float2 v;
                float a0 = h ? acc[p][0].y : acc[p][0].x;
                float a1 = h ? acc[p][1].y : acc[p][1].x;
                v.x = ACT ? silu_f(a0) : a0;
                v.y = ACT ? silu_f(a1) : a1;
                *reinterpret_cast<float2*>(op + (size_t)co * total + idx) = v;
            } else {
#pragma unroll
                for (int j4 = 0; j4 < PX / 4; ++j4) {
                    float4 v;
                    float a0 = h ? acc[p][4 * j4 + 0].y : acc[p][4 * j4 + 0].x;
                    float a1 = h ? acc[p][4 * j4 + 1].y : acc[p][4 * j4 + 1].x;
                    float a2 = h ? acc[p][4 * j4 + 2].y : acc[p][4 * j4 + 2].x;
                    float a3 = h ? acc[p][4 * j4 + 3].y : acc[p][4 * j4 + 3].x;
                    v.x = ACT ? silu_f(a0) : a0;
                    v.y = ACT ? silu_f(a1) : a1;
                    v.z = ACT ? silu_f(a2) : a2;
                    v.w = ACT ? silu_f(a3) : a3;
                    *reinterpret_cast<float4*>(op + (size_t)co * total + idx + 4 * j4) = v;
                }
            }
        }
    }
}

// ---------------------------------------------------------------------------
// Generic direct conv2d (SMALL convs): LDS weights (round-14/16 winner).
// ---------------------------------------------------------------------------
template<int CIN, int COUT, int KS, bool ACT, int PX>
__global__ __launch_bounds__(THREADS)
void conv_k(const float* __restrict__ in, const float* __restrict__ wt,
            const float* __restrict__ bias, float* __restrict__ out,
            int H, int lw, int bs_in, int bs_out)
{
    constexpr int PAD = (KS - 1) / 2;
    constexpr int K2 = KS * KS;
    constexpr int CO_S = (COUT + 3) & ~3;
    constexpr int WQ = CO_S / 4;
    constexpr int NP = COUT / 2;
    constexpr int RW = PX + KS - 1;
    constexpr int RW2 = (RW + 1) / 2;
    static_assert(COUT % 2 == 0, "");
    __shared__ float sw[CIN * K2 * CO_S];

    const int W = 1 << lw;
    const int total = H << lw;
    const int idx = (blockIdx.x * THREADS + threadIdx.x) * PX;
    const float* ip0 = in + (size_t)blockIdx.y * bs_in;
    float* op = out + (size_t)blockIdx.y * bs_out;
    const int x0 = idx & (W - 1);
    const int y  = idx >> lw;

    for (int i = threadIdx.x; i < CIN * K2 * COUT; i += THREADS)
        sw[(i / COUT) * CO_S + i % COUT] = wt[i];
    __syncthreads();

    f32x2 acc[NP][PX];
#pragma unroll
    for (int p = 0; p < NP; ++p) {
        f32x2 bb;
        bb.x = bias[2 * p];
        bb.y = bias[2 * p + 1];
#pragma unroll
        for (int j = 0; j < PX; ++j) acc[p][j] = bb;
    }

#pragma unroll 1
    for (int cl = 0; cl < CIN; ++cl) {
        const float* __restrict__ row0 = ip0 + (size_t)cl * total;
        f32x2 r2[KS][RW2];
#pragma unroll
        for (int ky = 0; ky < KS; ++ky) {
            const int yy = y + ky - PAD;
            load_row<KS, PX>((float*)r2[ky], row0 + (yy << lw),
                             (unsigned)yy < (unsigned)H, x0, W);
        }
        lds_taps<COUT, KS, PX, WQ, NP, RW2>(&sw[cl * K2 * CO_S], r2, acc);
    }

    conv_store<COUT, PX, ACT, NP>(op, total, idx, acc);
}

// ---------------------------------------------------------------------------
// Concat-fused conv2d: channel cl reads in0 (cl < C1) or in1 (cl - C1).
// Replaces copy_k + conv_k on the skip concats (round-17).
// ---------------------------------------------------------------------------
template<int C1, int C2, int COUT, int KS, bool ACT, int PX>
__global__ __launch_bounds__(THREADS)
void conv2in_k(const float* __restrict__ in0, const float* __restrict__ in1,
               const float* __restrict__ wt, const float* __restrict__ bias,
               float* __restrict__ out, int H, int lw,
               int bs_in0, int bs_in1, int bs_out)
{
    constexpr int CIN = C1 + C2;
    constexpr int PAD = (KS - 1) / 2;
    constexpr int K2 = KS * KS;
    constexpr int CO_S = (COUT + 3) & ~3;
    constexpr int WQ = CO_S / 4;
    constexpr int NP = COUT / 2;
    constexpr int RW = PX + KS - 1;
    constexpr int RW2 = (RW + 1) / 2;
    static_assert(COUT % 2 == 0, "");
    __shared__ float sw[CIN * K2 * CO_S];

    const int W = 1 << lw;
    const int total = H << lw;
    const int idx = (blockIdx.x * THREADS + threadIdx.x) * PX;
    const float* ip0 = in0 + (size_t)blockIdx.y * bs_in0;
    const float* ip1 = in1 + (size_t)blockIdx.y * bs_in1;
    float* op = out + (size_t)blockIdx.y * bs_out;
    const int x0 = idx & (W - 1);
    const int y  = idx >> lw;

    for (int i = threadIdx.x; i < CIN * K2 * COUT; i += THREADS)
        sw[(i / COUT) * CO_S + i % COUT] = wt[i];
    __syncthreads();

    f32x2 acc[NP][PX];
#pragma unroll
    for (int p = 0; p < NP; ++p) {
        f32x2 bb;
        bb.x = bias[2 * p];
        bb.y = bias[2 * p + 1];
#pragma unroll
        for (int j = 0; j < PX; ++j) acc[p][j] = bb;
    }

#pragma unroll 1
    for (int cl = 0; cl < CIN; ++cl) {
        const float* __restrict__ row0 =
            (cl < C1) ? (ip0 + (size_t)cl * total) : (ip1 + (size_t)(cl - C1) * total);
        f32x2 r2[KS][RW2];
#pragma unroll
        for (int ky = 0; ky < KS; ++ky) {
            const int yy = y + ky - PAD;
            load_row<KS, PX>((float*)r2[ky], row0 + (yy << lw),
                             (unsigned)yy < (unsigned)H, x0, W);
        }
        lds_taps<COUT, KS, PX, WQ, NP, RW2>(&sw[cl * K2 * CO_S], r2, acc);
    }

    conv_store<COUT, PX, ACT, NP>(op, total, idx, acc);
}

// ---------------------------------------------------------------------------
// DeformConv2d: 3x3, stride 1, pad 1, no bias. groups=2, offset groups=2.
// ---------------------------------------------------------------------------
template<int CIN, int COUT>
__global__ __launch_bounds__(THREADS)
void dconv_k(const float* __restrict__ in, const float* __restrict__ off,
             const float* __restrict__ twg0, const float* __restrict__ twg1,
             float* __restrict__ out,
             int H, int lw, int bs_in, int bs_off, int bs_out)
{
    constexpr int K = 9;
    constexpr int OG = 2;
    constexpr int COG = CIN / OG;
    constexpr int COUTG = COUT / 2;
    constexpr int NWG = COG * K * COUTG;
    __shared__ float sw[2 * NWG];
    for (int i = threadIdx.x; i < 2 * NWG; i += THREADS)
        sw[i] = (i < NWG) ? twg0[i] : twg1[i - NWG];
    __syncthreads();

    const int W = 1 << lw;
    const int total = H << lw;
    const int idx = blockIdx.x * THREADS + threadIdx.x;
    const float* ip0 = in + (size_t)blockIdx.y * bs_in;
    const float* offp = off + (size_t)blockIdx.y * bs_off;
    float* op = out + (size_t)blockIdx.y * bs_out;
    const int x = idx & (W - 1);
    const int y = idx >> lw;

    float acc[COUT];
#pragma unroll
    for (int co = 0; co < COUT; ++co) acc[co] = 0.f;

#pragma unroll
    for (int og = 0; og < OG; ++og) {
#pragma unroll
        for (int k = 0; k < K; ++k) {
            const int ki = k / 3 - 1;
            const int kj = k % 3 - 1;
            const float dy = offp[(size_t)(((og * K + k) * 2 + 0)) * total + idx];
            const float dx = offp[(size_t)(((og * K + k) * 2 + 1)) * total + idx];
            const float py = dy + (float)(y + ki);
            const float px = dx + (float)(x + kj);
            const float y0f = floorf(py), x0f = floorf(px);
            const float ly = py - y0f, lx = px - x0f;
            const int y0 = (int)y0f, x0 = (int)x0f;
            const int y1 = y0 + 1, x1 = x0 + 1;
            const bool vy0 = (unsigned)y0 < (unsigned)H;
            const bool vy1 = (unsigned)y1 < (unsigned)H;
            const bool vx0 = (unsigned)x0 < (unsigned)W;
            const bool vx1 = (unsigned)x1 < (unsigned)W;
            const int cy0 = min(max(y0, 0), H - 1), cy1 = min(max(y1, 0), H - 1);
            const int cx0 = min(max(x0, 0), W - 1), cx1 = min(max(x1, 0), W - 1);
            const int i00 = (cy0 << lw) + cx0, i01 = (cy0 << lw) + cx1;
            const int i10 = (cy1 << lw) + cx0, i11 = (cy1 << lw) + cx1;
            const float f00 = (vy0 && vx0) ? (1.f - ly) * (1.f - lx) : 0.f;
            const float f01 = (vy0 && vx1) ? (1.f - ly) * lx : 0.f;
            const float f10 = (vy1 && vx0) ? ly * (1.f - lx) : 0.f;
            const float f11 = (vy1 && vx1) ? ly * lx : 0.f;
            const float* swg = &sw[og * NWG];
#pragma unroll
            for (int c = 0; c < COG; ++c) {
                const float* __restrict__ ip = ip0 + (size_t)(og * COG + c) * total;
                const float v = f00 * ip[i00] + f01 * ip[i01]
                              + f10 * ip[i10] + f11 * ip[i11];
                const float* __restrict__ wr = &swg[(c * K + k) * COUTG];
#pragma unroll
                for (int col = 0; col < COUTG; ++col)
                    acc[og * COUTG + col] = fmaf(v, wr[col], acc[og * COUTG + col]);
            }
        }
    }

#pragma unroll
    for (int co = 0; co < COUT; ++co)
        op[(size_t)co * total + idx] = acc[co];
}

// 2x2 average pool.
__global__ __launch_bounds__(THREADS)
void avgpool_k(const float* __restrict__ in, float* __restrict__ out,
               int n, int lt, int lwo, int bsi, int bso)
{
    const int idx = blockIdx.x * THREADS + threadIdx.x;
    if (idx >= n) return;
    const float* ip0 = in + (size_t)blockIdx.y * bsi;
    float* op = out + (size_t)blockIdx.y * bso;
    const int c = idx >> lt;
    const int r = idx & ((1 << lt) - 1);
    const int oy = r >> lwo;
    const int ox = r & ((1 << lwo) - 1);
    const int Wi = 2 << lwo;
    const float* ip = ip0 + ((size_t)c << (lt + 2)) + ((size_t)(2 * oy) << (lwo + 1)) + 2 * ox;
    const float2 t = *reinterpret_cast<const float2*>(ip);
    const float2 b = *reinterpret_cast<const float2*>(ip + Wi);
    op[idx] = 0.25f * (t.x + t.y + b.x + b.y);
}

// Bilinear 2x upsample, align_corners=True.
__global__ __launch_bounds__(THREADS)
void up2x_k(const float* __restrict__ in, float* __restrict__ out,
            int n, int lt, int lwo, int Hin, int bsi, int bso)
{
    const int idx = blockIdx.x * THREADS + threadIdx.x;
    if (idx >= n) return;
    const float* ip0 = in + (size_t)blockIdx.y * bsi;
    float* op = out + (size_t)blockIdx.y * bso;
    const int c = idx >> lt;
    const int r = idx & ((1 << lt) - 1);
    const int oy = r >> lwo;
    const int ox = r & ((1 << lwo) - 1);
    const int W = 1 << (lwo - 1);
    const int H = Hin;
    const float s = (float)(H - 1) / (float)(2 * H - 1);
    const float fy = (float)oy * s;
    const float fx = (float)ox * s;
    const int y0 = (int)fy;
    const int x0 = (int)fx;
    const int y1 = min(y0 + 1, H - 1);
    const int x1 = min(x0 + 1, W - 1);
    const float wy = fy - (float)y0;
    const float wx = fx - (float)x0;
    const float* ip = ip0 + ((size_t)c << (lt - 2));
    const float v00 = ip[y0 * W + x0], v01 = ip[y0 * W + x1];
    const float v10 = ip[y1 * W + x0], v11 = ip[y1 * W + x1];
    op[idx] = (v00 * (1.f - wy) + v10 * wy) * (1.f - wx)
            + (v01 * (1.f - wy) + v11 * wy) * wx;
}

// ---------------------------------------------------------------------------

extern "C" void kernel_launch(void* const* d_in, const int* in_sizes, int n_in,
                              void* d_out, int out_size, void* d_ws, size_t ws_size,
                              hipStream_t stream) {
    const float* x      = (const float*)d_in[0];
    const float* eo1_b1 = (const float*)d_in[2];
    const float* eo1_b2 = (const float*)d_in[4];
    const float* c1d_b1 = (const float*)d_in[7];
    const float* c1d_b2 = (const float*)d_in[9];
    const float* eo2_b1 = (const float*)d_in[11];
    const float* eo2_b2 = (const float*)d_in[13];
    const float* c2d_b1 = (const float*)d_in[16];
    const float* c2d_b2 = (const float*)d_in[18];
    const float* eo3_b1 = (const float*)d_in[20];
    const float* eo3_b2 = (const float*)d_in[22];
    const float* c3d_b1 = (const float*)d_in[25];
    const float* c3d_b2 = (const float*)d_in[27];
    const float* up2_b  = (const float*)d_in[29];
    const float* c2u_b1 = (const float*)d_in[31];
    const float* c2u_b2 = (const float*)d_in[33];
    const float* up1_b  = (const float*)d_in[35];
    const float* c1u_b1 = (const float*)d_in[37];
    const float* c1u_b2 = (const float*)d_in[39];

    float* out = (float*)d_out;
    float* wsf = (float*)d_ws;

    constexpr int H1 = 512, A1 = H1 * H1;
    constexpr int H2 = 256, A2 = H2 * H2;
    constexpr int H3 = 128, A3 = H3 * H3;
    constexpr int TW_FLOATS = 81920;
    constexpr int SLOT = 58 * A1;
    constexpr int NCONV = 28;

    // ---- transposed-weight table: 28 conv entries + 6 dconv groups ----
    // eo1_w1 3xCO6 | eo1_b2 3xCO12 | c1d x2 | eo2_w1 3xCO6 | eo2_b2 3xCO12 |
    // c2d x2 | eo3_w1 | eo3_b2 3xCO12 | c3d x2 | up2 | c2u x2 | up1 | c1u x2
    const int widx[NCONV]  = {1, 1, 1,  3, 3, 3,  6, 8,
                              10, 10, 10,  12, 12, 12,  15, 17,
                              19,  21, 21, 21,  24, 26,
                              28, 30, 32, 34, 36, 38};
    const int wcin[NCONV]  = {4, 4, 4,  18, 18, 18,  2, 4,
                              8, 8, 8,  18, 18, 18,  8, 12,
                              16,  18, 18, 18,  16, 14,
                              12, 28, 16, 8, 16, 8};
    const int wcout[NCONV] = {6, 6, 6,  12, 12, 12,  4, 8,
                              6, 6, 6,  12, 12, 12,  12, 16,
                              18,  12, 12, 12,  14, 12,
                              12, 16, 8, 8, 8, 2};
    const int wk2[NCONV]   = {25, 25, 25,  25, 25, 25,  9, 9,
                              25, 25, 25,  25, 25, 25,  9, 9,
                              25,  25, 25, 25,  9, 9,
                              9, 9, 9, 9, 9, 9};
    const int wsoff[NCONV] = {0, 600, 1200,  0, 5400, 10800,  0, 0,
                              0, 1200, 2400,  0, 5400, 10800,  0, 0,
                              0,  0, 5400, 10800,  0, 0,
                              0, 0, 0, 0, 0, 0};
    const int cont[NCONV]  = {1, 1, 0,  1, 1, 0,  0, 0,
                              1, 1, 0,  1, 1, 0,  0, 0,
                              0,  1, 1, 0,  0, 0,
                              0, 0, 0, 0, 0, 0};
    TTab tab;
    const float* tw[40];
    int off = 0, base = 0;
    for (int i = 0; i < NCONV; ++i) {
        const int n = wcin[i] * wcout[i] * wk2[i];
        tab.e[i].src = (const float*)d_in[widx[i]] + wsoff[i];
        tab.e[i].dst = off; tab.e[i].cin = wcin[i]; tab.e[i].cout = wcout[i];
        tab.e[i].k2 = wk2[i]; tab.e[i].base = base; tab.e[i].n = n;
        tw[i] = wsf + off;
        off = cont[i] ? (off + n) : ((off + n + 63) & ~63);
        base += n;
    }
    const int didx[3]   = {5, 14, 23};
    const int dcoutg[3] = {1, 4, 8};
    const int dcpg[3]   = {2, 4, 8};
    for (int i = 0; i < 3; ++i) {
        for (int g = 0; g < 2; ++g) {
            const int e = NCONV + 2 * i + g;
            const int n = dcoutg[i] * dcpg[i] * 9;
            tab.e[e].src = (const float*)d_in[didx[i]] + (size_t)g * n;
            tab.e[e].dst = off; tab.e[e].cin = dcpg[i]; tab.e[e].cout = dcoutg[i];
            tab.e[e].k2 = 9; tab.e[e].base = base; tab.e[e].n = n;
            tw[e] = wsf + off;
            off = (off + n + 63) & ~63;
            base += n;
        }
    }
    tab.total = base;
    transpose_w_k<<<(base + THREADS - 1) / THREADS, THREADS, 0, stream>>>(tab, wsf);

    int B = 4;
    while (B > 1 && ws_size < ((size_t)TW_FLOATS + (size_t)B * SLOT) * sizeof(float)) B >>= 1;

    auto run_all = [&](int Bc, float* slot, int SB,
                       const float* xin, int xbs, float* outp, int obs) {
        float* S0 = slot;
        float* S1 = S0 + 36 * A1;
        float* S2 = S1 + 18 * A1;
        float* P  = S2 + 2 * A1;
        float* L1 = S1 + 10 * A1;
        float* L2 = S0 + 32 * A1;
        auto gs = [&](int n, int px, int z) { return dim3((n / (px * THREADS)) * Bc * z); };
        auto gp = [&](int n, int px) { return dim3(n / (px * THREADS), Bc); };
        auto g1 = [&](int n) { return dim3((n + THREADS - 1) / THREADS, Bc); };

        // ---- level 1 down ----
        conv_sl_k<4, 6, 5, false, 8><<<gs(A1, 8, 3), THREADS, 0, stream>>>(xin, tw[0], eo1_b1, S1, H1, 9, xbs, SB, Bc, 3);
        conv_sl_k<18, 12, 5, false, 8><<<gs(A1, 8, 3), THREADS, 0, stream>>>(S1, tw[3], eo1_b2, S0, H1, 9, SB, SB, Bc, 3);
        dconv_k<4, 2><<<g1(A1), THREADS, 0, stream>>>(xin, S0, tw[28], tw[29], S2, H1, 9, xbs, SB, SB);
        conv_k<2, 4, 3, true, 8><<<gp(A1, 8), THREADS, 0, stream>>>(S2, tw[6], c1d_b1, S1, H1, 9, SB, SB);
        conv_k<4, 8, 3, true, 8><<<gp(A1, 8), THREADS, 0, stream>>>(S1, tw[7], c1d_b2, L1, H1, 9, SB, SB);
        avgpool_k<<<g1(8 * A2), THREADS, 0, stream>>>(L1, P, 8 * A2, 16, 8, SB, SB);

        // ---- level 2 down ----
        conv_sl_k<8, 6, 5, false, 8><<<gs(A2, 8, 3), THREADS, 0, stream>>>(P, tw[8], eo2_b1, S1, H2, 8, SB, SB, Bc, 3);
        conv_sl_k<18, 12, 5, false, 8><<<gs(A2, 8, 3), THREADS, 0, stream>>>(S1, tw[11], eo2_b2, S0, H2, 8, SB, SB, Bc, 3);
        dconv_k<8, 8><<<g1(A2), THREADS, 0, stream>>>(P, S0, tw[30], tw[31], S2, H2, 8, SB, SB, SB);
        conv_k<8, 12, 3, true, 4><<<gp(A2, 4), THREADS, 0, stream>>>(S2, tw[14], c2d_b1, S1, H2, 8, SB, SB);
        conv_k<12, 16, 3, true, 4><<<gp(A2, 4), THREADS, 0, stream>>>(S1, tw[15], c2d_b2, L2, H2, 8, SB, SB);
        avgpool_k<<<g1(16 * A3), THREADS, 0, stream>>>(L2, P, 16 * A3, 14, 7, SB, SB);

        // ---- level 3 (bottleneck) ----
        conv_k<16, 18, 5, false, 2><<<gp(A3, 2), THREADS, 0, stream>>>(P, tw[16], eo3_b1, S1, H3, 7, SB, SB);
        conv_sl_k<18, 12, 5, false, 4><<<gs(A3, 4, 3), THREADS, 0, stream>>>(S1, tw[17], eo3_b2, S0, H3, 7, SB, SB, Bc, 3);
        dconv_k<16, 16><<<g1(A3), THREADS, 0, stream>>>(P, S0, tw[32], tw[33], S2, H3, 7, SB, SB, SB);
        conv_k<16, 14, 3, true, 2><<<gp(A3, 2), THREADS, 0, stream>>>(S2, tw[20], c3d_b1, S1, H3, 7, SB, SB);
        conv_k<14, 12, 3, true, 2><<<gp(A3, 2), THREADS, 0, stream>>>(S1, tw[21], c3d_b2, S2, H3, 7, SB, SB);

        // ---- up path level 2 ----
        up2x_k<<<g1(12 * A2), THREADS, 0, stream>>>(S2, S0, 12 * A2, 16, 8, H3, SB, SB);
        conv_k<12, 12, 3, true, 4><<<gp(A2, 4), THREADS, 0, stream>>>(S0, tw[22], up2_b, S1, H2, 8, SB, SB);
        conv2in_k<12, 16, 16, 3, true, 4><<<gp(A2, 4), THREADS, 0, stream>>>(S1, L2, tw[23], c2u_b1, S0, H2, 8, SB, SB, SB);
        conv_k<16, 8, 3, true, 4><<<gp(A2, 4), THREADS, 0, stream>>>(S0, tw[24], c2u_b2, S2, H2, 8, SB, SB);

        // ---- up path level 1 ----
        up2x_k<<<g1(8 * A1), THREADS, 0, stream>>>(S2, S0, 8 * A1, 18, 9, H2, SB, SB);
        conv_k<8, 8, 3, true, 8><<<gp(A1, 8), THREADS, 0, stream>>>(S0, tw[25], up1_b, S0 + 8 * A1, H1, 9, SB, SB);
        conv2in_k<8, 8, 8, 3, true, 8><<<gp(A1, 8), THREADS, 0, stream>>>(S0 + 8 * A1, L1, tw[26], c1u_b1, S1, H1, 9, SB, SB, SB);
        conv_k<8, 2, 3, true, 8><<<gp(A1, 8), THREADS, 0, stream>>>(S1, tw[27], c1u_b2, outp, H1, 9, SB, obs);
    };

    for (int g = 0; g < 4; g += B)
        run_all(B, wsf + TW_FLOATS, SLOT,
                x + (size_t)g * 4 * A1, 4 * A1,
                out + (size_t)g * 2 * A1, 2 * A1);
}

// Round 18
// 1361.297 us; speedup vs baseline: 1.1890x; 1.0317x over previous
//
#include <hip/hip_runtime.h>
#include <math.h>

#define THREADS 256
typedef __attribute__((ext_vector_type(2))) float f32x2;
typedef __attribute__((ext_vector_type(4))) float f32x4;

__device__ __forceinline__ float silu_f(float v) {
    return v / (1.f + __expf(-v));
}

// packed fp32 fma, VGPR weight pair
__device__ __forceinline__ void pk_fma_lo(f32x2& d, f32x2 a, f32x2 b) {
    asm("v_pk_fma_f32 %0, %1, %2, %0 op_sel:[0,0,0] op_sel_hi:[0,1,1]"
        : "+v"(d) : "v"(a), "v"(b));
}
__device__ __forceinline__ void pk_fma_hi(f32x2& d, f32x2 a, f32x2 b) {
    asm("v_pk_fma_f32 %0, %1, %2, %0 op_sel:[1,0,0] op_sel_hi:[1,1,1]"
        : "+v"(d) : "v"(a), "v"(b));
}
// packed fp32 fma, SGPR weight pair (one scalar source legal on VOP3P)
__device__ __forceinline__ void pk_fma_lo_s(f32x2& d, f32x2 a, f32x2 b) {
    asm("v_pk_fma_f32 %0, %1, %2, %0 op_sel:[0,0,0] op_sel_hi:[0,1,1]"
        : "+v"(d) : "v"(a), "s"(b));
}
__device__ __forceinline__ void pk_fma_hi_s(f32x2& d, f32x2 a, f32x2 b) {
    asm("v_pk_fma_f32 %0, %1, %2, %0 op_sel:[1,0,0] op_sel_hi:[1,1,1]"
        : "+v"(d) : "v"(a), "s"(b));
}

// ---------------------------------------------------------------------------
// Weight transpose: [co][ci][k2] -> [ci][k2][co]
// ---------------------------------------------------------------------------
struct TEnt { const float* src; int dst; int cin; int cout; int k2; int base; int n; };
struct TTab { TEnt e[40]; int total; };

__global__ __launch_bounds__(THREADS)
void transpose_w_k(TTab t, float* __restrict__ tw) {
    const int i = blockIdx.x * THREADS + threadIdx.x;
    if (i >= t.total) return;
    int j = 0;
    while (i >= t.e[j].base + t.e[j].n) ++j;
    const TEnt e = t.e[j];
    const int local = i - e.base;
    const int co  = local % e.cout;
    const int tmp = local / e.cout;
    const int k   = tmp % e.k2;
    const int ci  = tmp / e.k2;
    tw[e.dst + local] = e.src[(co * e.cin + ci) * e.k2 + k];
}

// aligned-chunk row loader; interior chunks skip per-lane x checks.
template<int KS, int PX>
__device__ __forceinline__ void load_row(float* __restrict__ rr,
                                         const float* __restrict__ rp,
                                         bool vy, int x0, int W)
{
    constexpr int PAD = (KS - 1) / 2;
    constexpr int RW = PX + KS - 1;
#pragma unroll
    for (int q = -1; q <= PX / 4; ++q) {
        if (4 * q + 3 + PAD < 0 || 4 * q + PAD >= RW) continue;
        const int xs = x0 + 4 * q;
        const bool safe = (q >= 0) && (4 * q + 3 < PX);
        float vc[4] = {0.f, 0.f, 0.f, 0.f};
        if (safe) {
            if (vy) {
                const float4 v = *reinterpret_cast<const float4*>(rp + xs);
                vc[0] = v.x; vc[1] = v.y; vc[2] = v.z; vc[3] = v.w;
            }
        } else if (vy && xs >= 0 && xs + 4 <= W) {
            const float4 v = *reinterpret_cast<const float4*>(rp + xs);
            vc[0] = v.x; vc[1] = v.y; vc[2] = v.z; vc[3] = v.w;
        } else if (vy) {
#pragma unroll
            for (int c = 0; c < 4; ++c)
                vc[c] = ((unsigned)(xs + c) < (unsigned)W) ? rp[xs + c] : 0.f;
        }
#pragma unroll
        for (int c = 0; c < 4; ++c) {
            const int t = 4 * q + c + PAD;
            if (t >= 0 && t < RW) rr[t] = vc[c];
        }
    }
}

// ---------------------------------------------------------------------------
// SGPR-weight per-channel body (round-15 win for big convs).
// ---------------------------------------------------------------------------
template<int CIN, int COUT, int KS, int PX, int PHASE, int RW2, int NP>
__device__ __forceinline__ void chan_body(
    const float* __restrict__ ip0, const float* __restrict__ wz,
    int cl, int y, int x0, int W, int H, int lw, int total,
    f32x2 (&r2)[2][RW2], f32x2 (&wb)[2][NP], f32x2 (&acc)[NP][PX])
{
    constexpr int PAD = (KS - 1) / 2;
    constexpr int K2 = KS * KS;
    static_assert(K2 % 2 == 1, "parity continuity needs odd K2");
#pragma unroll
    for (int ky = 0; ky < KS; ++ky) {
        {
            const bool last = (ky + 1 == KS);
            const int ncl = cl + (last ? 1 : 0);
            const int nky = last ? 0 : (ky + 1);
            if (!last || ncl < CIN) {
                const int yy = y + nky - PAD;
                load_row<KS, PX>((float*)r2[(PHASE + ky + 1) & 1],
                                 ip0 + (size_t)ncl * total + (yy << lw),
                                 (unsigned)yy < (unsigned)H, x0, W);
            }
        }
#pragma unroll
        for (int kx = 0; kx < KS; ++kx) {
            const int t = ky * KS + kx;
            const int wc = (PHASE + t) & 1;
            if (t + 1 < K2 || cl + 1 < CIN) {
                const f32x2* __restrict__ nx =
                    (const f32x2*)(wz + (size_t)(cl * K2 + t + 1) * COUT);
#pragma unroll
                for (int p = 0; p < NP; ++p) wb[wc ^ 1][p] = nx[p];
            }
#pragma unroll
            for (int p = 0; p < NP; ++p) {
                const f32x2 wp = wb[wc][p];
#pragma unroll
                for (int j = 0; j < PX; ++j) {
                    const int e = kx + j;
                    if (e & 1) pk_fma_hi_s(acc[p][j], r2[(PHASE + ky) & 1][e >> 1], wp);
                    else       pk_fma_lo_s(acc[p][j], r2[(PHASE + ky) & 1][e >> 1], wp);
                }
            }
            __builtin_amdgcn_sched_barrier(0);
        }
    }
}

// ---------------------------------------------------------------------------
// Sliced direct conv2d (BIG 5x5 convs), SGPR weights, XCD-grouped 1-D grid.
// CO12 slices (round-17). Round-18: PX chosen for grid fill >= 3 blocks/CU.
// ---------------------------------------------------------------------------
template<int CIN, int COUT, int KS, bool ACT, int PX>
__global__ __launch_bounds__(THREADS)
void conv_sl_k(const float* __restrict__ in, const float* __restrict__ wt,
               const float* __restrict__ bias, float* __restrict__ out,
               int H, int lw, int bs_in, int bs_out, int nb, int nz)
{
    constexpr int PAD = (KS - 1) / 2;
    constexpr int K2 = KS * KS;
    constexpr int NP = COUT / 2;
    constexpr int RW = PX + KS - 1;
    constexpr int RW2 = (RW + 1) / 2;
    static_assert(CIN % 2 == 0 && COUT % 2 == 0 && PX % 4 == 0, "");

    const int lin = blockIdx.x;
    const int r8 = lin & 7;
    int q = lin >> 3;
    const int z = q % nz; q /= nz;
    const int g = q * 8 + r8;
    const int b = g % nb;
    const int xb = g / nb;

    const float* __restrict__ wz = wt + (size_t)z * (CIN * K2 * COUT);
    const int W = 1 << lw;
    const int total = H << lw;
    const int idx = (xb * THREADS + threadIdx.x) * PX;
    const float* ip0 = in + (size_t)b * bs_in;
    float* op = out + (size_t)b * bs_out + (size_t)z * COUT * total;
    const int x0 = idx & (W - 1);
    const int y  = idx >> lw;

    f32x2 acc[NP][PX];
#pragma unroll
    for (int p = 0; p < NP; ++p) {
        f32x2 bb;
        bb.x = bias[z * COUT + 2 * p];
        bb.y = bias[z * COUT + 2 * p + 1];
#pragma unroll
        for (int j = 0; j < PX; ++j) acc[p][j] = bb;
    }

    f32x2 r2[2][RW2];
    f32x2 wb[2][NP];
    {
        const int yy = y - PAD;
        load_row<KS, PX>((float*)r2[0], ip0 + (yy << lw),
                         (unsigned)yy < (unsigned)H, x0, W);
        const f32x2* __restrict__ w0 = (const f32x2*)wz;
#pragma unroll
        for (int p = 0; p < NP; ++p) wb[0][p] = w0[p];
    }

#pragma unroll 1
    for (int c2 = 0; c2 < CIN / 2; ++c2) {
        chan_body<CIN, COUT, KS, PX, 0, RW2, NP>(ip0, wz, 2 * c2,     y, x0, W, H, lw, total, r2, wb, acc);
        chan_body<CIN, COUT, KS, PX, 1, RW2, NP>(ip0, wz, 2 * c2 + 1, y, x0, W, H, lw, total, r2, wb, acc);
    }

#pragma unroll
    for (int p = 0; p < NP; ++p) {
#pragma unroll
        for (int h = 0; h < 2; ++h) {
            const int co = 2 * p + h;
#pragma unroll
            for (int j4 = 0; j4 < PX / 4; ++j4) {
                float4 v;
                float a0 = h ? acc[p][4 * j4 + 0].y : acc[p][4 * j4 + 0].x;
                float a1 = h ? acc[p][4 * j4 + 1].y : acc[p][4 * j4 + 1].x;
                float a2 = h ? acc[p][4 * j4 + 2].y : acc[p][4 * j4 + 2].x;
                float a3 = h ? acc[p][4 * j4 + 3].y : acc[p][4 * j4 + 3].x;
                v.x = ACT ? silu_f(a0) : a0;
                v.y = ACT ? silu_f(a1) : a1;
                v.z = ACT ? silu_f(a2) : a2;
                v.w = ACT ? silu_f(a3) : a3;
                *reinterpret_cast<float4*>(op + (size_t)co * total + idx + 4 * j4) = v;
            }
        }
    }
}

// ---------------------------------------------------------------------------
// Shared LDS-weight tap sweep for the small convs.
// ---------------------------------------------------------------------------
template<int COUT, int KS, int PX, int WQ, int NP, int RW2>
__device__ __forceinline__ void lds_taps(
    const float* __restrict__ wbase, f32x2 (&r2)[KS][RW2], f32x2 (&acc)[NP][PX])
{
    constexpr int K2 = KS * KS;
    constexpr int CO_S = (COUT + 3) & ~3;
#pragma unroll
    for (int t = 0; t < K2; ++t) {
        const int ky = t / KS, kx = t % KS;
        const f32x4* __restrict__ wv = (const f32x4*)(wbase + t * CO_S);
#pragma unroll
        for (int q = 0; q < WQ; ++q) {
            const f32x4 w4 = wv[q];
            const f32x2 wlo = __builtin_shufflevector(w4, w4, 0, 1);
            const f32x2 whi = __builtin_shufflevector(w4, w4, 2, 3);
#pragma unroll
            for (int s = 0; s < 2; ++s) {
                const int p = 2 * q + s;
                if (p < NP) {
                    const f32x2 wp = s ? whi : wlo;
#pragma unroll
                    for (int j = 0; j < PX; ++j) {
                        const int e = kx + j;
                        if (e & 1) pk_fma_hi(acc[p][j], r2[ky][e >> 1], wp);
                        else       pk_fma_lo(acc[p][j], r2[ky][e >> 1], wp);
                    }
                }
            }
        }
        __builtin_amdgcn_sched_barrier(0);
    }
}

template<int COUT, int PX, bool ACT, int NP>
__device__ __forceinline__ void conv_store(
    float* __restrict__ op, int total, int idx, f32x2 (&acc)[NP][PX])
{
#pragma unroll
    for (int p = 0; p < NP; ++p) {
#pragma unroll
        for (int h = 0; h < 2; ++h) {
            const int co = 2 * p + h;
            if (PX == 2) {
                float2 v;
                float a0 = h ? acc[p][0].y : acc[p][0].x;
                float a1 = h ? acc[p][1].y : acc[p][1].x;
                v.x = ACT ? silu_f(a0) : a0;
                v.y = ACT ? silu_f(a1) : a1;
                *reinterpret_cast<float2*>(op + (size_t)co * total + idx) = v;
            } else {
#pragma unroll
                for (int j4 = 0; j4 < PX / 4; ++j4) {
                    float4 v;
                    float a0 = h ? acc[p][4 * j4 + 0].y : acc[p][4 * j4 + 0].x;
                    float a1 = h ? acc[p][4 * j4 + 1].y : acc[p][4 * j4 + 1].x;
                    float a2 = h ? acc[p][4 * j4 + 2].y : acc[p][4 * j4 + 2].x;
                    float a3 = h ? acc[p][4 * j4 + 3].y : acc[p][4 * j4 + 3].x;
                    v.x = ACT ? silu_f(a0) : a0;
                    v.y = ACT ? silu_f(a1) : a1;
                    v.z = ACT ? silu_f(a2) : a2;
                    v.w = ACT ? silu_f(a3) : a3;
                    *reinterpret_cast<float4*>(op + (size_t)co * total + idx + 4 * j4) = v;
                }
            }
        }
    }
}

// ---------------------------------------------------------------------------
// Generic direct conv2d (SMALL convs): LDS weights (round-14/16 winner).
// ---------------------------------------------------------------------------
template<int CIN, int COUT, int KS, bool ACT, int PX>
__global__ __launch_bounds__(THREADS)
void conv_k(const float* __restrict__ in, const float* __restrict__ wt,
            const float* __restrict__ bias, float* __restrict__ out,
            int H, int lw, int bs_in, int bs_out)
{
    constexpr int PAD = (KS - 1) / 2;
    constexpr int K2 = KS * KS;
    constexpr int CO_S = (COUT + 3) & ~3;
    constexpr int WQ = CO_S / 4;
    constexpr int NP = COUT / 2;
    constexpr int RW = PX + KS - 1;
    constexpr int RW2 = (RW + 1) / 2;
    static_assert(COUT % 2 == 0, "");
    __shared__ float sw[CIN * K2 * CO_S];

    const int W = 1 << lw;
    const int total = H << lw;
    const int idx = (blockIdx.x * THREADS + threadIdx.x) * PX;
    const float* ip0 = in + (size_t)blockIdx.y * bs_in;
    float* op = out + (size_t)blockIdx.y * bs_out;
    const int x0 = idx & (W - 1);
    const int y  = idx >> lw;

    for (int i = threadIdx.x; i < CIN * K2 * COUT; i += THREADS)
        sw[(i / COUT) * CO_S + i % COUT] = wt[i];
    __syncthreads();

    f32x2 acc[NP][PX];
#pragma unroll
    for (int p = 0; p < NP; ++p) {
        f32x2 bb;
        bb.x = bias[2 * p];
        bb.y = bias[2 * p + 1];
#pragma unroll
        for (int j = 0; j < PX; ++j) acc[p][j] = bb;
    }

#pragma unroll 1
    for (int cl = 0; cl < CIN; ++cl) {
        const float* __restrict__ row0 = ip0 + (size_t)cl * total;
        f32x2 r2[KS][RW2];
#pragma unroll
        for (int ky = 0; ky < KS; ++ky) {
            const int yy = y + ky - PAD;
            load_row<KS, PX>((float*)r2[ky], row0 + (yy << lw),
                             (unsigned)yy < (unsigned)H, x0, W);
        }
        lds_taps<COUT, KS, PX, WQ, NP, RW2>(&sw[cl * K2 * CO_S], r2, acc);
    }

    conv_store<COUT, PX, ACT, NP>(op, total, idx, acc);
}

// ---------------------------------------------------------------------------
// Concat-fused conv2d: channel cl reads in0 (cl < C1) or in1 (cl - C1).
// ---------------------------------------------------------------------------
template<int C1, int C2, int COUT, int KS, bool ACT, int PX>
__global__ __launch_bounds__(THREADS)
void conv2in_k(const float* __restrict__ in0, const float* __restrict__ in1,
               const float* __restrict__ wt, const float* __restrict__ bias,
               float* __restrict__ out, int H, int lw,
               int bs_in0, int bs_in1, int bs_out)
{
    constexpr int CIN = C1 + C2;
    constexpr int PAD = (KS - 1) / 2;
    constexpr int K2 = KS * KS;
    constexpr int CO_S = (COUT + 3) & ~3;
    constexpr int WQ = CO_S / 4;
    constexpr int NP = COUT / 2;
    constexpr int RW = PX + KS - 1;
    constexpr int RW2 = (RW + 1) / 2;
    static_assert(COUT % 2 == 0, "");
    __shared__ float sw[CIN * K2 * CO_S];

    const int W = 1 << lw;
    const int total = H << lw;
    const int idx = (blockIdx.x * THREADS + threadIdx.x) * PX;
    const float* ip0 = in0 + (size_t)blockIdx.y * bs_in0;
    const float* ip1 = in1 + (size_t)blockIdx.y * bs_in1;
    float* op = out + (size_t)blockIdx.y * bs_out;
    const int x0 = idx & (W - 1);
    const int y  = idx >> lw;

    for (int i = threadIdx.x; i < CIN * K2 * COUT; i += THREADS)
        sw[(i / COUT) * CO_S + i % COUT] = wt[i];
    __syncthreads();

    f32x2 acc[NP][PX];
#pragma unroll
    for (int p = 0; p < NP; ++p) {
        f32x2 bb;
        bb.x = bias[2 * p];
        bb.y = bias[2 * p + 1];
#pragma unroll
        for (int j = 0; j < PX; ++j) acc[p][j] = bb;
    }

#pragma unroll 1
    for (int cl = 0; cl < CIN; ++cl) {
        const float* __restrict__ row0 =
            (cl < C1) ? (ip0 + (size_t)cl * total) : (ip1 + (size_t)(cl - C1) * total);
        f32x2 r2[KS][RW2];
#pragma unroll
        for (int ky = 0; ky < KS; ++ky) {
            const int yy = y + ky - PAD;
            load_row<KS, PX>((float*)r2[ky], row0 + (yy << lw),
                             (unsigned)yy < (unsigned)H, x0, W);
        }
        lds_taps<COUT, KS, PX, WQ, NP, RW2>(&sw[cl * K2 * CO_S], r2, acc);
    }

    conv_store<COUT, PX, ACT, NP>(op, total, idx, acc);
}

// ---------------------------------------------------------------------------
// DeformConv2d: 3x3, stride 1, pad 1, no bias. groups=2, offset groups=2.
// ---------------------------------------------------------------------------
template<int CIN, int COUT>
__global__ __launch_bounds__(THREADS)
void dconv_k(const float* __restrict__ in, const float* __restrict__ off,
             const float* __restrict__ twg0, const float* __restrict__ twg1,
             float* __restrict__ out,
             int H, int lw, int bs_in, int bs_off, int bs_out)
{
    constexpr int K = 9;
    constexpr int OG = 2;
    constexpr int COG = CIN / OG;
    constexpr int COUTG = COUT / 2;
    constexpr int NWG = COG * K * COUTG;
    __shared__ float sw[2 * NWG];
    for (int i = threadIdx.x; i < 2 * NWG; i += THREADS)
        sw[i] = (i < NWG) ? twg0[i] : twg1[i - NWG];
    __syncthreads();

    const int W = 1 << lw;
    const int total = H << lw;
    const int idx = blockIdx.x * THREADS + threadIdx.x;
    const float* ip0 = in + (size_t)blockIdx.y * bs_in;
    const float* offp = off + (size_t)blockIdx.y * bs_off;
    float* op = out + (size_t)blockIdx.y * bs_out;
    const int x = idx & (W - 1);
    const int y = idx >> lw;

    float acc[COUT];
#pragma unroll
    for (int co = 0; co < COUT; ++co) acc[co] = 0.f;

#pragma unroll
    for (int og = 0; og < OG; ++og) {
#pragma unroll
        for (int k = 0; k < K; ++k) {
            const int ki = k / 3 - 1;
            const int kj = k % 3 - 1;
            const float dy = offp[(size_t)(((og * K + k) * 2 + 0)) * total + idx];
            const float dx = offp[(size_t)(((og * K + k) * 2 + 1)) * total + idx];
            const float py = dy + (float)(y + ki);
            const float px = dx + (float)(x + kj);
            const float y0f = floorf(py), x0f = floorf(px);
            const float ly = py - y0f, lx = px - x0f;
            const int y0 = (int)y0f, x0 = (int)x0f;
            const int y1 = y0 + 1, x1 = x0 + 1;
            const bool vy0 = (unsigned)y0 < (unsigned)H;
            const bool vy1 = (unsigned)y1 < (unsigned)H;
            const bool vx0 = (unsigned)x0 < (unsigned)W;
            const bool vx1 = (unsigned)x1 < (unsigned)W;
            const int cy0 = min(max(y0, 0), H - 1), cy1 = min(max(y1, 0), H - 1);
            const int cx0 = min(max(x0, 0), W - 1), cx1 = min(max(x1, 0), W - 1);
            const int i00 = (cy0 << lw) + cx0, i01 = (cy0 << lw) + cx1;
            const int i10 = (cy1 << lw) + cx0, i11 = (cy1 << lw) + cx1;
            const float f00 = (vy0 && vx0) ? (1.f - ly) * (1.f - lx) : 0.f;
            const float f01 = (vy0 && vx1) ? (1.f - ly) * lx : 0.f;
            const float f10 = (vy1 && vx0) ? ly * (1.f - lx) : 0.f;
            const float f11 = (vy1 && vx1) ? ly * lx : 0.f;
            const float* swg = &sw[og * NWG];
#pragma unroll
            for (int c = 0; c < COG; ++c) {
                const float* __restrict__ ip = ip0 + (size_t)(og * COG + c) * total;
                const float v = f00 * ip[i00] + f01 * ip[i01]
                              + f10 * ip[i10] + f11 * ip[i11];
                const float* __restrict__ wr = &swg[(c * K + k) * COUTG];
#pragma unroll
                for (int col = 0; col < COUTG; ++col)
                    acc[og * COUTG + col] = fmaf(v, wr[col], acc[og * COUTG + col]);
            }
        }
    }

#pragma unroll
    for (int co = 0; co < COUT; ++co)
        op[(size_t)co * total + idx] = acc[co];
}

// 2x2 average pool.
__global__ __launch_bounds__(THREADS)
void avgpool_k(const float* __restrict__ in, float* __restrict__ out,
               int n, int lt, int lwo, int bsi, int bso)
{
    const int idx = blockIdx.x * THREADS + threadIdx.x;
    if (idx >= n) return;
    const float* ip0 = in + (size_t)blockIdx.y * bsi;
    float* op = out + (size_t)blockIdx.y * bso;
    const int c = idx >> lt;
    const int r = idx & ((1 << lt) - 1);
    const int oy = r >> lwo;
    const int ox = r & ((1 << lwo) - 1);
    const int Wi = 2 << lwo;
    const float* ip = ip0 + ((size_t)c << (lt + 2)) + ((size_t)(2 * oy) << (lwo + 1)) + 2 * ox;
    const float2 t = *reinterpret_cast<const float2*>(ip);
    const float2 b = *reinterpret_cast<const float2*>(ip + Wi);
    op[idx] = 0.25f * (t.x + t.y + b.x + b.y);
}

// Bilinear 2x upsample, align_corners=True.
__global__ __launch_bounds__(THREADS)
void up2x_k(const float* __restrict__ in, float* __restrict__ out,
            int n, int lt, int lwo, int Hin, int bsi, int bso)
{
    const int idx = blockIdx.x * THREADS + threadIdx.x;
    if (idx >= n) return;
    const float* ip0 = in + (size_t)blockIdx.y * bsi;
    float* op = out + (size_t)blockIdx.y * bso;
    const int c = idx >> lt;
    const int r = idx & ((1 << lt) - 1);
    const int oy = r >> lwo;
    const int ox = r & ((1 << lwo) - 1);
    const int W = 1 << (lwo - 1);
    const int H = Hin;
    const float s = (float)(H - 1) / (float)(2 * H - 1);
    const float fy = (float)oy * s;
    const float fx = (float)ox * s;
    const int y0 = (int)fy;
    const int x0 = (int)fx;
    const int y1 = min(y0 + 1, H - 1);
    const int x1 = min(x0 + 1, W - 1);
    const float wy = fy - (float)y0;
    const float wx = fx - (float)x0;
    const float* ip = ip0 + ((size_t)c << (lt - 2));
    const float v00 = ip[y0 * W + x0], v01 = ip[y0 * W + x1];
    const float v10 = ip[y1 * W + x0], v11 = ip[y1 * W + x1];
    op[idx] = (v00 * (1.f - wy) + v10 * wy) * (1.f - wx)
            + (v01 * (1.f - wy) + v11 * wy) * wx;
}

// ---------------------------------------------------------------------------

extern "C" void kernel_launch(void* const* d_in, const int* in_sizes, int n_in,
                              void* d_out, int out_size, void* d_ws, size_t ws_size,
                              hipStream_t stream) {
    const float* x      = (const float*)d_in[0];
    const float* eo1_b1 = (const float*)d_in[2];
    const float* eo1_b2 = (const float*)d_in[4];
    const float* c1d_b1 = (const float*)d_in[7];
    const float* c1d_b2 = (const float*)d_in[9];
    const float* eo2_b1 = (const float*)d_in[11];
    const float* eo2_b2 = (const float*)d_in[13];
    const float* c2d_b1 = (const float*)d_in[16];
    const float* c2d_b2 = (const float*)d_in[18];
    const float* eo3_b1 = (const float*)d_in[20];
    const float* eo3_b2 = (const float*)d_in[22];
    const float* c3d_b1 = (const float*)d_in[25];
    const float* c3d_b2 = (const float*)d_in[27];
    const float* up2_b  = (const float*)d_in[29];
    const float* c2u_b1 = (const float*)d_in[31];
    const float* c2u_b2 = (const float*)d_in[33];
    const float* up1_b  = (const float*)d_in[35];
    const float* c1u_b1 = (const float*)d_in[37];
    const float* c1u_b2 = (const float*)d_in[39];

    float* out = (float*)d_out;
    float* wsf = (float*)d_ws;

    constexpr int H1 = 512, A1 = H1 * H1;
    constexpr int H2 = 256, A2 = H2 * H2;
    constexpr int H3 = 128, A3 = H3 * H3;
    constexpr int TW_FLOATS = 81920;
    constexpr int SLOT = 58 * A1;
    constexpr int NCONV = 28;

    // ---- transposed-weight table: 28 conv entries + 6 dconv groups ----
    const int widx[NCONV]  = {1, 1, 1,  3, 3, 3,  6, 8,
                              10, 10, 10,  12, 12, 12,  15, 17,
                              19,  21, 21, 21,  24, 26,
                              28, 30, 32, 34, 36, 38};
    const int wcin[NCONV]  = {4, 4, 4,  18, 18, 18,  2, 4,
                              8, 8, 8,  18, 18, 18,  8, 12,
                              16,  18, 18, 18,  16, 14,
                              12, 28, 16, 8, 16, 8};
    const int wcout[NCONV] = {6, 6, 6,  12, 12, 12,  4, 8,
                              6, 6, 6,  12, 12, 12,  12, 16,
                              18,  12, 12, 12,  14, 12,
                              12, 16, 8, 8, 8, 2};
    const int wk2[NCONV]   = {25, 25, 25,  25, 25, 25,  9, 9,
                              25, 25, 25,  25, 25, 25,  9, 9,
                              25,  25, 25, 25,  9, 9,
                              9, 9, 9, 9, 9, 9};
    const int wsoff[NCONV] = {0, 600, 1200,  0, 5400, 10800,  0, 0,
                              0, 1200, 2400,  0, 5400, 10800,  0, 0,
                              0,  0, 5400, 10800,  0, 0,
                              0, 0, 0, 0, 0, 0};
    const int cont[NCONV]  = {1, 1, 0,  1, 1, 0,  0, 0,
                              1, 1, 0,  1, 1, 0,  0, 0,
                              0,  1, 1, 0,  0, 0,
                              0, 0, 0, 0, 0, 0};
    TTab tab;
    const float* tw[40];
    int off = 0, base = 0;
    for (int i = 0; i < NCONV; ++i) {
        const int n = wcin[i] * wcout[i] * wk2[i];
        tab.e[i].src = (const float*)d_in[widx[i]] + wsoff[i];
        tab.e[i].dst = off; tab.e[i].cin = wcin[i]; tab.e[i].cout = wcout[i];
        tab.e[i].k2 = wk2[i]; tab.e[i].base = base; tab.e[i].n = n;
        tw[i] = wsf + off;
        off = cont[i] ? (off + n) : ((off + n + 63) & ~63);
        base += n;
    }
    const int didx[3]   = {5, 14, 23};
    const int dcoutg[3] = {1, 4, 8};
    const int dcpg[3]   = {2, 4, 8};
    for (int i = 0; i < 3; ++i) {
        for (int g = 0; g < 2; ++g) {
            const int e = NCONV + 2 * i + g;
            const int n = dcoutg[i] * dcpg[i] * 9;
            tab.e[e].src = (const float*)d_in[didx[i]] + (size_t)g * n;
            tab.e[e].dst = off; tab.e[e].cin = dcpg[i]; tab.e[e].cout = dcoutg[i];
            tab.e[e].k2 = 9; tab.e[e].base = base; tab.e[e].n = n;
            tw[e] = wsf + off;
            off = (off + n + 63) & ~63;
            base += n;
        }
    }
    tab.total = base;
    transpose_w_k<<<(base + THREADS - 1) / THREADS, THREADS, 0, stream>>>(tab, wsf);

    int B = 4;
    while (B > 1 && ws_size < ((size_t)TW_FLOATS + (size_t)B * SLOT) * sizeof(float)) B >>= 1;

    auto run_all = [&](int Bc, float* slot, int SB,
                       const float* xin, int xbs, float* outp, int obs) {
        float* S0 = slot;
        float* S1 = S0 + 36 * A1;
        float* S2 = S1 + 18 * A1;
        float* P  = S2 + 2 * A1;
        float* L1 = S1 + 10 * A1;
        float* L2 = S0 + 32 * A1;
        auto gs = [&](int n, int px, int z) { return dim3((n / (px * THREADS)) * Bc * z); };
        auto gp = [&](int n, int px) { return dim3(n / (px * THREADS), Bc); };
        auto g1 = [&](int n) { return dim3((n + THREADS - 1) / THREADS, Bc); };

        // ---- level 1 down ----
        conv_sl_k<4, 6, 5, false, 8><<<gs(A1, 8, 3), THREADS, 0, stream>>>(xin, tw[0], eo1_b1, S1, H1, 9, xbs, SB, Bc, 3);
        conv_sl_k<18, 12, 5, false, 8><<<gs(A1, 8, 3), THREADS, 0, stream>>>(S1, tw[3], eo1_b2, S0, H1, 9, SB, SB, Bc, 3);
        dconv_k<4, 2><<<g1(A1), THREADS, 0, stream>>>(xin, S0, tw[28], tw[29], S2, H1, 9, xbs, SB, SB);
        conv_k<2, 4, 3, true, 4><<<gp(A1, 4), THREADS, 0, stream>>>(S2, tw[6], c1d_b1, S1, H1, 9, SB, SB);
        conv_k<4, 8, 3, true, 4><<<gp(A1, 4), THREADS, 0, stream>>>(S1, tw[7], c1d_b2, L1, H1, 9, SB, SB);
        avgpool_k<<<g1(8 * A2), THREADS, 0, stream>>>(L1, P, 8 * A2, 16, 8, SB, SB);

        // ---- level 2 down ----
        conv_sl_k<8, 6, 5, false, 4><<<gs(A2, 4, 3), THREADS, 0, stream>>>(P, tw[8], eo2_b1, S1, H2, 8, SB, SB, Bc, 3);
        conv_sl_k<18, 12, 5, false, 4><<<gs(A2, 4, 3), THREADS, 0, stream>>>(S1, tw[11], eo2_b2, S0, H2, 8, SB, SB, Bc, 3);
        dconv_k<8, 8><<<g1(A2), THREADS, 0, stream>>>(P, S0, tw[30], tw[31], S2, H2, 8, SB, SB, SB);
        conv_k<8, 12, 3, true, 2><<<gp(A2, 2), THREADS, 0, stream>>>(S2, tw[14], c2d_b1, S1, H2, 8, SB, SB);
        conv_k<12, 16, 3, true, 2><<<gp(A2, 2), THREADS, 0, stream>>>(S1, tw[15], c2d_b2, L2, H2, 8, SB, SB);
        avgpool_k<<<g1(16 * A3), THREADS, 0, stream>>>(L2, P, 16 * A3, 14, 7, SB, SB);

        // ---- level 3 (bottleneck) ----
        conv_k<16, 18, 5, false, 2><<<gp(A3, 2), THREADS, 0, stream>>>(P, tw[16], eo3_b1, S1, H3, 7, SB, SB);
        conv_sl_k<18, 12, 5, false, 4><<<gs(A3, 4, 3), THREADS, 0, stream>>>(S1, tw[17], eo3_b2, S0, H3, 7, SB, SB, Bc, 3);
        dconv_k<16, 16><<<g1(A3), THREADS, 0, stream>>>(P, S0, tw[32], tw[33], S2, H3, 7, SB, SB, SB);
        conv_k<16, 14, 3, true, 2><<<gp(A3, 2), THREADS, 0, stream>>>(S2, tw[20], c3d_b1, S1, H3, 7, SB, SB);
        conv_k<14, 12, 3, true, 2><<<gp(A3, 2), THREADS, 0, stream>>>(S1, tw[21], c3d_b2, S2, H3, 7, SB, SB);

        // ---- up path level 2 ----
        up2x_k<<<g1(12 * A2), THREADS, 0, stream>>>(S2, S0, 12 * A2, 16, 8, H3, SB, SB);
        conv_k<12, 12, 3, true, 2><<<gp(A2, 2), THREADS, 0, stream>>>(S0, tw[22], up2_b, S1, H2, 8, SB, SB);
        conv2in_k<12, 16, 16, 3, true, 2><<<gp(A2, 2), THREADS, 0, stream>>>(S1, L2, tw[23], c2u_b1, S0, H2, 8, SB, SB, SB);
        conv_k<16, 8, 3, true, 2><<<gp(A2, 2), THREADS, 0, stream>>>(S0, tw[24], c2u_b2, S2, H2, 8, SB, SB);

        // ---- up path level 1 ----
        up2x_k<<<g1(8 * A1), THREADS, 0, stream>>>(S2, S0, 8 * A1, 18, 9, H2, SB, SB);
        conv_k<8, 8, 3, true, 4><<<gp(A1, 4), THREADS, 0, stream>>>(S0, tw[25], up1_b, S0 + 8 * A1, H1, 9, SB, SB);
        conv2in_k<8, 8, 8, 3, true, 4><<<gp(A1, 4), THREADS, 0, stream>>>(S0 + 8 * A1, L1, tw[26], c1u_b1, S1, H1, 9, SB, SB, SB);
        conv_k<8, 2, 3, true, 4><<<gp(A1, 4), THREADS, 0, stream>>>(S1, tw[27], c1u_b2, outp, H1, 9, SB, obs);
    };

    for (int g = 0; g < 4; g += B)
        run_all(B, wsf + TW_FLOATS, SLOT,
                x + (size_t)g * 4 * A1, 4 * A1,
                out + (size_t)g * 2 * A1, 2 * A1);
}

// Round 19
// 1357.427 us; speedup vs baseline: 1.1924x; 1.0029x over previous
//
#include <hip/hip_runtime.h>
#include <math.h>

#define THREADS 256
typedef __attribute__((ext_vector_type(2))) float f32x2;
typedef __attribute__((ext_vector_type(4))) float f32x4;

__device__ __forceinline__ float silu_f(float v) {
    return v / (1.f + __expf(-v));
}

// packed fp32 fma, VGPR weight pair
__device__ __forceinline__ void pk_fma_lo(f32x2& d, f32x2 a, f32x2 b) {
    asm("v_pk_fma_f32 %0, %1, %2, %0 op_sel:[0,0,0] op_sel_hi:[0,1,1]"
        : "+v"(d) : "v"(a), "v"(b));
}
__device__ __forceinline__ void pk_fma_hi(f32x2& d, f32x2 a, f32x2 b) {
    asm("v_pk_fma_f32 %0, %1, %2, %0 op_sel:[1,0,0] op_sel_hi:[1,1,1]"
        : "+v"(d) : "v"(a), "v"(b));
}
// packed fp32 fma, SGPR weight pair (one scalar source legal on VOP3P)
__device__ __forceinline__ void pk_fma_lo_s(f32x2& d, f32x2 a, f32x2 b) {
    asm("v_pk_fma_f32 %0, %1, %2, %0 op_sel:[0,0,0] op_sel_hi:[0,1,1]"
        : "+v"(d) : "v"(a), "s"(b));
}
__device__ __forceinline__ void pk_fma_hi_s(f32x2& d, f32x2 a, f32x2 b) {
    asm("v_pk_fma_f32 %0, %1, %2, %0 op_sel:[1,0,0] op_sel_hi:[1,1,1]"
        : "+v"(d) : "v"(a), "s"(b));
}

// ---------------------------------------------------------------------------
// Weight transpose: [co][ci][k2] -> [ci][k2][co]
// ---------------------------------------------------------------------------
struct TEnt { const float* src; int dst; int cin; int cout; int k2; int base; int n; };
struct TTab { TEnt e[40]; int total; };

__global__ __launch_bounds__(THREADS)
void transpose_w_k(TTab t, float* __restrict__ tw) {
    const int i = blockIdx.x * THREADS + threadIdx.x;
    if (i >= t.total) return;
    int j = 0;
    while (i >= t.e[j].base + t.e[j].n) ++j;
    const TEnt e = t.e[j];
    const int local = i - e.base;
    const int co  = local % e.cout;
    const int tmp = local / e.cout;
    const int k   = tmp % e.k2;
    const int ci  = tmp / e.k2;
    tw[e.dst + local] = e.src[(co * e.cin + ci) * e.k2 + k];
}

// aligned-chunk row loader; interior chunks skip per-lane x checks.
template<int KS, int PX>
__device__ __forceinline__ void load_row(float* __restrict__ rr,
                                         const float* __restrict__ rp,
                                         bool vy, int x0, int W)
{
    constexpr int PAD = (KS - 1) / 2;
    constexpr int RW = PX + KS - 1;
#pragma unroll
    for (int q = -1; q <= PX / 4; ++q) {
        if (4 * q + 3 + PAD < 0 || 4 * q + PAD >= RW) continue;
        const int xs = x0 + 4 * q;
        const bool safe = (q >= 0) && (4 * q + 3 < PX);
        float vc[4] = {0.f, 0.f, 0.f, 0.f};
        if (safe) {
            if (vy) {
                const float4 v = *reinterpret_cast<const float4*>(rp + xs);
                vc[0] = v.x; vc[1] = v.y; vc[2] = v.z; vc[3] = v.w;
            }
        } else if (vy && xs >= 0 && xs + 4 <= W) {
            const float4 v = *reinterpret_cast<const float4*>(rp + xs);
            vc[0] = v.x; vc[1] = v.y; vc[2] = v.z; vc[3] = v.w;
        } else if (vy) {
#pragma unroll
            for (int c = 0; c < 4; ++c)
                vc[c] = ((unsigned)(xs + c) < (unsigned)W) ? rp[xs + c] : 0.f;
        }
#pragma unroll
        for (int c = 0; c < 4; ++c) {
            const int t = 4 * q + c + PAD;
            if (t >= 0 && t < RW) rr[t] = vc[c];
        }
    }
}

// ---------------------------------------------------------------------------
// SGPR-weight per-channel body. Round-19: fence relaxed to per-ky (5 walls
// per channel instead of 25) — safe because weights live in SGPRs (plentiful)
// and the 2-buffer row rotation bounds VGPR hoisting via WAR deps. The
// round-4 spill was LDS b128 VGPR weights; that hazard no longer exists here.
// ---------------------------------------------------------------------------
template<int CIN, int COUT, int KS, int PX, int PHASE, int RW2, int NP>
__device__ __forceinline__ void chan_body(
    const float* __restrict__ ip0, const float* __restrict__ wz,
    int cl, int y, int x0, int W, int H, int lw, int total,
    f32x2 (&r2)[2][RW2], f32x2 (&wb)[2][NP], f32x2 (&acc)[NP][PX])
{
    constexpr int PAD = (KS - 1) / 2;
    constexpr int K2 = KS * KS;
    static_assert(K2 % 2 == 1, "parity continuity needs odd K2");
#pragma unroll
    for (int ky = 0; ky < KS; ++ky) {
        {
            const bool last = (ky + 1 == KS);
            const int ncl = cl + (last ? 1 : 0);
            const int nky = last ? 0 : (ky + 1);
            if (!last || ncl < CIN) {
                const int yy = y + nky - PAD;
                load_row<KS, PX>((float*)r2[(PHASE + ky + 1) & 1],
                                 ip0 + (size_t)ncl * total + (yy << lw),
                                 (unsigned)yy < (unsigned)H, x0, W);
            }
        }
#pragma unroll
        for (int kx = 0; kx < KS; ++kx) {
            const int t = ky * KS + kx;
            const int wc = (PHASE + t) & 1;
            if (t + 1 < K2 || cl + 1 < CIN) {
                const f32x2* __restrict__ nx =
                    (const f32x2*)(wz + (size_t)(cl * K2 + t + 1) * COUT);
#pragma unroll
                for (int p = 0; p < NP; ++p) wb[wc ^ 1][p] = nx[p];
            }
#pragma unroll
            for (int p = 0; p < NP; ++p) {
                const f32x2 wp = wb[wc][p];
#pragma unroll
                for (int j = 0; j < PX; ++j) {
                    const int e = kx + j;
                    if (e & 1) pk_fma_hi_s(acc[p][j], r2[(PHASE + ky) & 1][e >> 1], wp);
                    else       pk_fma_lo_s(acc[p][j], r2[(PHASE + ky) & 1][e >> 1], wp);
                }
            }
        }
        __builtin_amdgcn_sched_barrier(0);   // per-ky wall (round-19)
    }
}

// ---------------------------------------------------------------------------
// Sliced direct conv2d (BIG 5x5 convs), SGPR weights, XCD-grouped 1-D grid.
// ---------------------------------------------------------------------------
template<int CIN, int COUT, int KS, bool ACT, int PX>
__global__ __launch_bounds__(THREADS)
void conv_sl_k(const float* __restrict__ in, const float* __restrict__ wt,
               const float* __restrict__ bias, float* __restrict__ out,
               int H, int lw, int bs_in, int bs_out, int nb, int nz)
{
    constexpr int PAD = (KS - 1) / 2;
    constexpr int K2 = KS * KS;
    constexpr int NP = COUT / 2;
    constexpr int RW = PX + KS - 1;
    constexpr int RW2 = (RW + 1) / 2;
    static_assert(CIN % 2 == 0 && COUT % 2 == 0 && PX % 4 == 0, "");

    const int lin = blockIdx.x;
    const int r8 = lin & 7;
    int q = lin >> 3;
    const int z = q % nz; q /= nz;
    const int g = q * 8 + r8;
    const int b = g % nb;
    const int xb = g / nb;

    const float* __restrict__ wz = wt + (size_t)z * (CIN * K2 * COUT);
    const int W = 1 << lw;
    const int total = H << lw;
    const int idx = (xb * THREADS + threadIdx.x) * PX;
    const float* ip0 = in + (size_t)b * bs_in;
    float* op = out + (size_t)b * bs_out + (size_t)z * COUT * total;
    const int x0 = idx & (W - 1);
    const int y  = idx >> lw;

    f32x2 acc[NP][PX];
#pragma unroll
    for (int p = 0; p < NP; ++p) {
        f32x2 bb;
        bb.x = bias[z * COUT + 2 * p];
        bb.y = bias[z * COUT + 2 * p + 1];
#pragma unroll
        for (int j = 0; j < PX; ++j) acc[p][j] = bb;
    }

    f32x2 r2[2][RW2];
    f32x2 wb[2][NP];
    {
        const int yy = y - PAD;
        load_row<KS, PX>((float*)r2[0], ip0 + (yy << lw),
                         (unsigned)yy < (unsigned)H, x0, W);
        const f32x2* __restrict__ w0 = (const f32x2*)wz;
#pragma unroll
        for (int p = 0; p < NP; ++p) wb[0][p] = w0[p];
    }

#pragma unroll 1
    for (int c2 = 0; c2 < CIN / 2; ++c2) {
        chan_body<CIN, COUT, KS, PX, 0, RW2, NP>(ip0, wz, 2 * c2,     y, x0, W, H, lw, total, r2, wb, acc);
        chan_body<CIN, COUT, KS, PX, 1, RW2, NP>(ip0, wz, 2 * c2 + 1, y, x0, W, H, lw, total, r2, wb, acc);
    }

#pragma unroll
    for (int p = 0; p < NP; ++p) {
#pragma unroll
        for (int h = 0; h < 2; ++h) {
            const int co = 2 * p + h;
#pragma unroll
            for (int j4 = 0; j4 < PX / 4; ++j4) {
                float4 v;
                float a0 = h ? acc[p][4 * j4 + 0].y : acc[p][4 * j4 + 0].x;
                float a1 = h ? acc[p][4 * j4 + 1].y : acc[p][4 * j4 + 1].x;
                float a2 = h ? acc[p][4 * j4 + 2].y : acc[p][4 * j4 + 2].x;
                float a3 = h ? acc[p][4 * j4 + 3].y : acc[p][4 * j4 + 3].x;
                v.x = ACT ? silu_f(a0) : a0;
                v.y = ACT ? silu_f(a1) : a1;
                v.z = ACT ? silu_f(a2) : a2;
                v.w = ACT ? silu_f(a3) : a3;
                *reinterpret_cast<float4*>(op + (size_t)co * total + idx + 4 * j4) = v;
            }
        }
    }
}

// ---------------------------------------------------------------------------
// Shared LDS-weight tap sweep (per-tap fence kept: VGPR weight vectors are
// the round-4 hoisting hazard).
// ---------------------------------------------------------------------------
template<int COUT, int KS, int PX, int WQ, int NP, int RW2>
__device__ __forceinline__ void lds_taps(
    const float* __restrict__ wbase, f32x2 (&r2)[KS][RW2], f32x2 (&acc)[NP][PX])
{
    constexpr int K2 = KS * KS;
    constexpr int CO_S = (COUT + 3) & ~3;
#pragma unroll
    for (int t = 0; t < K2; ++t) {
        const int ky = t / KS, kx = t % KS;
        const f32x4* __restrict__ wv = (const f32x4*)(wbase + t * CO_S);
#pragma unroll
        for (int q = 0; q < WQ; ++q) {
            const f32x4 w4 = wv[q];
            const f32x2 wlo = __builtin_shufflevector(w4, w4, 0, 1);
            const f32x2 whi = __builtin_shufflevector(w4, w4, 2, 3);
#pragma unroll
            for (int s = 0; s < 2; ++s) {
                const int p = 2 * q + s;
                if (p < NP) {
                    const f32x2 wp = s ? whi : wlo;
#pragma unroll
                    for (int j = 0; j < PX; ++j) {
                        const int e = kx + j;
                        if (e & 1) pk_fma_hi(acc[p][j], r2[ky][e >> 1], wp);
                        else       pk_fma_lo(acc[p][j], r2[ky][e >> 1], wp);
                    }
                }
            }
        }
        __builtin_amdgcn_sched_barrier(0);
    }
}

template<int COUT, int PX, bool ACT, int NP>
__device__ __forceinline__ void conv_store(
    float* __restrict__ op, int total, int idx, f32x2 (&acc)[NP][PX])
{
#pragma unroll
    for (int p = 0; p < NP; ++p) {
#pragma unroll
        for (int h = 0; h < 2; ++h) {
            const int co = 2 * p + h;
            if (PX == 2) {
                float2 v;
                float a0 = h ? acc[p][0].y : acc[p][0].x;
                float a1 = h ? acc[p][1].y : acc[p][1].x;
                v.x = ACT ? silu_f(a0) : a0;
                v.y = ACT ? silu_f(a1) : a1;
                *reinterpret_cast<float2*>(op + (size_t)co * total + idx) = v;
            } else {
#pragma unroll
                for (int j4 = 0; j4 < PX / 4; ++j4) {
                    float4 v;
                    float a0 = h ? acc[p][4 * j4 + 0].y : acc[p][4 * j4 + 0].x;
                    float a1 = h ? acc[p][4 * j4 + 1].y : acc[p][4 * j4 + 1].x;
                    float a2 = h ? acc[p][4 * j4 + 2].y : acc[p][4 * j4 + 2].x;
                    float a3 = h ? acc[p][4 * j4 + 3].y : acc[p][4 * j4 + 3].x;
                    v.x = ACT ? silu_f(a0) : a0;
                    v.y = ACT ? silu_f(a1) : a1;
                    v.z = ACT ? silu_f(a2) : a2;
                    v.w = ACT ? silu_f(a3) : a3;
                    *reinterpret_cast<float4*>(op + (size_t)co * total + idx + 4 * j4) = v;
                }
            }
        }
    }
}

// ---------------------------------------------------------------------------
// Generic direct conv2d (SMALL convs): LDS weights.
// ---------------------------------------------------------------------------
template<int CIN, int COUT, int KS, bool ACT, int PX>
__global__ __launch_bounds__(THREADS)
void conv_k(const float* __restrict__ in, const float* __restrict__ wt,
            const float* __restrict__ bias, float* __restrict__ out,
            int H, int lw, int bs_in, int bs_out)
{
    constexpr int PAD = (KS - 1) / 2;
    constexpr int K2 = KS * KS;
    constexpr int CO_S = (COUT + 3) & ~3;
    constexpr int WQ = CO_S / 4;
    constexpr int NP = COUT / 2;
    constexpr int RW = PX + KS - 1;
    constexpr int RW2 = (RW + 1) / 2;
    static_assert(COUT % 2 == 0, "");
    __shared__ float sw[CIN * K2 * CO_S];

    const int W = 1 << lw;
    const int total = H << lw;
    const int idx = (blockIdx.x * THREADS + threadIdx.x) * PX;
    const float* ip0 = in + (size_t)blockIdx.y * bs_in;
    float* op = out + (size_t)blockIdx.y * bs_out;
    const int x0 = idx & (W - 1);
    const int y  = idx >> lw;

    for (int i = threadIdx.x; i < CIN * K2 * COUT; i += THREADS)
        sw[(i / COUT) * CO_S + i % COUT] = wt[i];
    __syncthreads();

    f32x2 acc[NP][PX];
#pragma unroll
    for (int p = 0; p < NP; ++p) {
        f32x2 bb;
        bb.x = bias[2 * p];
        bb.y = bias[2 * p + 1];
#pragma unroll
        for (int j = 0; j < PX; ++j) acc[p][j] = bb;
    }

#pragma unroll 1
    for (int cl = 0; cl < CIN; ++cl) {
        const float* __restrict__ row0 = ip0 + (size_t)cl * total;
        f32x2 r2[KS][RW2];
#pragma unroll
        for (int ky = 0; ky < KS; ++ky) {
            const int yy = y + ky - PAD;
            load_row<KS, PX>((float*)r2[ky], row0 + (yy << lw),
                             (unsigned)yy < (unsigned)H, x0, W);
        }
        lds_taps<COUT, KS, PX, WQ, NP, RW2>(&sw[cl * K2 * CO_S], r2, acc);
    }

    conv_store<COUT, PX, ACT, NP>(op, total, idx, acc);
}

// ---------------------------------------------------------------------------
// Concat-fused conv2d: channel cl reads in0 (cl < C1) or in1 (cl - C1).
// ---------------------------------------------------------------------------
template<int C1, int C2, int COUT, int KS, bool ACT, int PX>
__global__ __launch_bounds__(THREADS)
void conv2in_k(const float* __restrict__ in0, const float* __restrict__ in1,
               const float* __restrict__ wt, const float* __restrict__ bias,
               float* __restrict__ out, int H, int lw,
               int bs_in0, int bs_in1, int bs_out)
{
    constexpr int CIN = C1 + C2;
    constexpr int PAD = (KS - 1) / 2;
    constexpr int K2 = KS * KS;
    constexpr int CO_S = (COUT + 3) & ~3;
    constexpr int WQ = CO_S / 4;
    constexpr int NP = COUT / 2;
    constexpr int RW = PX + KS - 1;
    constexpr int RW2 = (RW + 1) / 2;
    static_assert(COUT % 2 == 0, "");
    __shared__ float sw[CIN * K2 * CO_S];

    const int W = 1 << lw;
    const int total = H << lw;
    const int idx = (blockIdx.x * THREADS + threadIdx.x) * PX;
    const float* ip0 = in0 + (size_t)blockIdx.y * bs_in0;
    const float* ip1 = in1 + (size_t)blockIdx.y * bs_in1;
    float* op = out + (size_t)blockIdx.y * bs_out;
    const int x0 = idx & (W - 1);
    const int y  = idx >> lw;

    for (int i = threadIdx.x; i < CIN * K2 * COUT; i += THREADS)
        sw[(i / COUT) * CO_S + i % COUT] = wt[i];
    __syncthreads();

    f32x2 acc[NP][PX];
#pragma unroll
    for (int p = 0; p < NP; ++p) {
        f32x2 bb;
        bb.x = bias[2 * p];
        bb.y = bias[2 * p + 1];
#pragma unroll
        for (int j = 0; j < PX; ++j) acc[p][j] = bb;
    }

#pragma unroll 1
    for (int cl = 0; cl < CIN; ++cl) {
        const float* __restrict__ row0 =
            (cl < C1) ? (ip0 + (size_t)cl * total) : (ip1 + (size_t)(cl - C1) * total);
        f32x2 r2[KS][RW2];
#pragma unroll
        for (int ky = 0; ky < KS; ++ky) {
            const int yy = y + ky - PAD;
            load_row<KS, PX>((float*)r2[ky], row0 + (yy << lw),
                             (unsigned)yy < (unsigned)H, x0, W);
        }
        lds_taps<COUT, KS, PX, WQ, NP, RW2>(&sw[cl * K2 * CO_S], r2, acc);
    }

    conv_store<COUT, PX, ACT, NP>(op, total, idx, acc);
}

// ---------------------------------------------------------------------------
// DeformConv2d: 3x3, stride 1, pad 1, no bias. groups=2, offset groups=2.
// ---------------------------------------------------------------------------
template<int CIN, int COUT>
__global__ __launch_bounds__(THREADS)
void dconv_k(const float* __restrict__ in, const float* __restrict__ off,
             const float* __restrict__ twg0, const float* __restrict__ twg1,
             float* __restrict__ out,
             int H, int lw, int bs_in, int bs_off, int bs_out)
{
    constexpr int K = 9;
    constexpr int OG = 2;
    constexpr int COG = CIN / OG;
    constexpr int COUTG = COUT / 2;
    constexpr int NWG = COG * K * COUTG;
    __shared__ float sw[2 * NWG];
    for (int i = threadIdx.x; i < 2 * NWG; i += THREADS)
        sw[i] = (i < NWG) ? twg0[i] : twg1[i - NWG];
    __syncthreads();

    const int W = 1 << lw;
    const int total = H << lw;
    const int idx = blockIdx.x * THREADS + threadIdx.x;
    const float* ip0 = in + (size_t)blockIdx.y * bs_in;
    const float* offp = off + (size_t)blockIdx.y * bs_off;
    float* op = out + (size_t)blockIdx.y * bs_out;
    const int x = idx & (W - 1);
    const int y = idx >> lw;

    float acc[COUT];
#pragma unroll
    for (int co = 0; co < COUT; ++co) acc[co] = 0.f;

#pragma unroll
    for (int og = 0; og < OG; ++og) {
#pragma unroll
        for (int k = 0; k < K; ++k) {
            const int ki = k / 3 - 1;
            const int kj = k % 3 - 1;
            const float dy = offp[(size_t)(((og * K + k) * 2 + 0)) * total + idx];
            const float dx = offp[(size_t)(((og * K + k) * 2 + 1)) * total + idx];
            const float py = dy + (float)(y + ki);
            const float px = dx + (float)(x + kj);
            const float y0f = floorf(py), x0f = floorf(px);
            const float ly = py - y0f, lx = px - x0f;
            const int y0 = (int)y0f, x0 = (int)x0f;
            const int y1 = y0 + 1, x1 = x0 + 1;
            const bool vy0 = (unsigned)y0 < (unsigned)H;
            const bool vy1 = (unsigned)y1 < (unsigned)H;
            const bool vx0 = (unsigned)x0 < (unsigned)W;
            const bool vx1 = (unsigned)x1 < (unsigned)W;
            const int cy0 = min(max(y0, 0), H - 1), cy1 = min(max(y1, 0), H - 1);
            const int cx0 = min(max(x0, 0), W - 1), cx1 = min(max(x1, 0), W - 1);
            const int i00 = (cy0 << lw) + cx0, i01 = (cy0 << lw) + cx1;
            const int i10 = (cy1 << lw) + cx0, i11 = (cy1 << lw) + cx1;
            const float f00 = (vy0 && vx0) ? (1.f - ly) * (1.f - lx) : 0.f;
            const float f01 = (vy0 && vx1) ? (1.f - ly) * lx : 0.f;
            const float f10 = (vy1 && vx0) ? ly * (1.f - lx) : 0.f;
            const float f11 = (vy1 && vx1) ? ly * lx : 0.f;
            const float* swg = &sw[og * NWG];
#pragma unroll
            for (int c = 0; c < COG; ++c) {
                const float* __restrict__ ip = ip0 + (size_t)(og * COG + c) * total;
                const float v = f00 * ip[i00] + f01 * ip[i01]
                              + f10 * ip[i10] + f11 * ip[i11];
                const float* __restrict__ wr = &swg[(c * K + k) * COUTG];
#pragma unroll
                for (int col = 0; col < COUTG; ++col)
                    acc[og * COUTG + col] = fmaf(v, wr[col], acc[og * COUTG + col]);
            }
        }
    }

#pragma unroll
    for (int co = 0; co < COUT; ++co)
        op[(size_t)co * total + idx] = acc[co];
}

// 2x2 average pool.
__global__ __launch_bounds__(THREADS)
void avgpool_k(const float* __restrict__ in, float* __restrict__ out,
               int n, int lt, int lwo, int bsi, int bso)
{
    const int idx = blockIdx.x * THREADS + threadIdx.x;
    if (idx >= n) return;
    const float* ip0 = in + (size_t)blockIdx.y * bsi;
    float* op = out + (size_t)blockIdx.y * bso;
    const int c = idx >> lt;
    const int r = idx & ((1 << lt) - 1);
    const int oy = r >> lwo;
    const int ox = r & ((1 << lwo) - 1);
    const int Wi = 2 << lwo;
    const float* ip = ip0 + ((size_t)c << (lt + 2)) + ((size_t)(2 * oy) << (lwo + 1)) + 2 * ox;
    const float2 t = *reinterpret_cast<const float2*>(ip);
    const float2 b = *reinterpret_cast<const float2*>(ip + Wi);
    op[idx] = 0.25f * (t.x + t.y + b.x + b.y);
}

// Bilinear 2x upsample, align_corners=True.
__global__ __launch_bounds__(THREADS)
void up2x_k(const float* __restrict__ in, float* __restrict__ out,
            int n, int lt, int lwo, int Hin, int bsi, int bso)
{
    const int idx = blockIdx.x * THREADS + threadIdx.x;
    if (idx >= n) return;
    const float* ip0 = in + (size_t)blockIdx.y * bsi;
    float* op = out + (size_t)blockIdx.y * bso;
    const int c = idx >> lt;
    const int r = idx & ((1 << lt) - 1);
    const int oy = r >> lwo;
    const int ox = r & ((1 << lwo) - 1);
    const int W = 1 << (lwo - 1);
    const int H = Hin;
    const float s = (float)(H - 1) / (float)(2 * H - 1);
    const float fy = (float)oy * s;
    const float fx = (float)ox * s;
    const int y0 = (int)fy;
    const int x0 = (int)fx;
    const int y1 = min(y0 + 1, H - 1);
    const int x1 = min(x0 + 1, W - 1);
    const float wy = fy - (float)y0;
    const float wx = fx - (float)x0;
    const float* ip = ip0 + ((size_t)c << (lt - 2));
    const float v00 = ip[y0 * W + x0], v01 = ip[y0 * W + x1];
    const float v10 = ip[y1 * W + x0], v11 = ip[y1 * W + x1];
    op[idx] = (v00 * (1.f - wy) + v10 * wy) * (1.f - wx)
            + (v01 * (1.f - wy) + v11 * wy) * wx;
}

// ---------------------------------------------------------------------------

extern "C" void kernel_launch(void* const* d_in, const int* in_sizes, int n_in,
                              void* d_out, int out_size, void* d_ws, size_t ws_size,
                              hipStream_t stream) {
    const float* x      = (const float*)d_in[0];
    const float* eo1_b1 = (const float*)d_in[2];
    const float* eo1_b2 = (const float*)d_in[4];
    const float* c1d_b1 = (const float*)d_in[7];
    const float* c1d_b2 = (const float*)d_in[9];
    const float* eo2_b1 = (const float*)d_in[11];
    const float* eo2_b2 = (const float*)d_in[13];
    const float* c2d_b1 = (const float*)d_in[16];
    const float* c2d_b2 = (const float*)d_in[18];
    const float* eo3_b1 = (const float*)d_in[20];
    const float* eo3_b2 = (const float*)d_in[22];
    const float* c3d_b1 = (const float*)d_in[25];
    const float* c3d_b2 = (const float*)d_in[27];
    const float* up2_b  = (const float*)d_in[29];
    const float* c2u_b1 = (const float*)d_in[31];
    const float* c2u_b2 = (const float*)d_in[33];
    const float* up1_b  = (const float*)d_in[35];
    const float* c1u_b1 = (const float*)d_in[37];
    const float* c1u_b2 = (const float*)d_in[39];

    float* out = (float*)d_out;
    float* wsf = (float*)d_ws;

    constexpr int H1 = 512, A1 = H1 * H1;
    constexpr int H2 = 256, A2 = H2 * H2;
    constexpr int H3 = 128, A3 = H3 * H3;
    constexpr int TW_FLOATS = 81920;
    constexpr int SLOT = 58 * A1;
    constexpr int NCONV = 26;

    // ---- transposed-weight table: 26 conv entries + 6 dconv groups ----
    // eo1_w1 CO18 (merged, round-19) | eo1_b2 3xCO12 | c1d x2 |
    // eo2_w1 3xCO6 | eo2_b2 3xCO12 | c2d x2 | eo3_w1 | eo3_b2 3xCO12 |
    // c3d x2 | up2 | c2u x2 | up1 | c1u x2
    const int widx[NCONV]  = {1,  3, 3, 3,  6, 8,
                              10, 10, 10,  12, 12, 12,  15, 17,
                              19,  21, 21, 21,  24, 26,
                              28, 30, 32, 34, 36, 38};
    const int wcin[NCONV]  = {4,  18, 18, 18,  2, 4,
                              8, 8, 8,  18, 18, 18,  8, 12,
                              16,  18, 18, 18,  16, 14,
                              12, 28, 16, 8, 16, 8};
    const int wcout[NCONV] = {18,  12, 12, 12,  4, 8,
                              6, 6, 6,  12, 12, 12,  12, 16,
                              18,  12, 12, 12,  14, 12,
                              12, 16, 8, 8, 8, 2};
    const int wk2[NCONV]   = {25,  25, 25, 25,  9, 9,
                              25, 25, 25,  25, 25, 25,  9, 9,
                              25,  25, 25, 25,  9, 9,
                              9, 9, 9, 9, 9, 9};
    const int wsoff[NCONV] = {0,  0, 5400, 10800,  0, 0,
                              0, 1200, 2400,  0, 5400, 10800,  0, 0,
                              0,  0, 5400, 10800,  0, 0,
                              0, 0, 0, 0, 0, 0};
    const int cont[NCONV]  = {0,  1, 1, 0,  0, 0,
                              1, 1, 0,  1, 1, 0,  0, 0,
                              0,  1, 1, 0,  0, 0,
                              0, 0, 0, 0, 0, 0};
    TTab tab;
    const float* tw[40];
    int off = 0, base = 0;
    for (int i = 0; i < NCONV; ++i) {
        const int n = wcin[i] * wcout[i] * wk2[i];
        tab.e[i].src = (const float*)d_in[widx[i]] + wsoff[i];
        tab.e[i].dst = off; tab.e[i].cin = wcin[i]; tab.e[i].cout = wcout[i];
        tab.e[i].k2 = wk2[i]; tab.e[i].base = base; tab.e[i].n = n;
        tw[i] = wsf + off;
        off = cont[i] ? (off + n) : ((off + n + 63) & ~63);
        base += n;
    }
    const int didx[3]   = {5, 14, 23};
    const int dcoutg[3] = {1, 4, 8};
    const int dcpg[3]   = {2, 4, 8};
    for (int i = 0; i < 3; ++i) {
        for (int g = 0; g < 2; ++g) {
            const int e = NCONV + 2 * i + g;
            const int n = dcoutg[i] * dcpg[i] * 9;
            tab.e[e].src = (const float*)d_in[didx[i]] + (size_t)g * n;
            tab.e[e].dst = off; tab.e[e].cin = dcpg[i]; tab.e[e].cout = dcoutg[i];
            tab.e[e].k2 = 9; tab.e[e].base = base; tab.e[e].n = n;
            tw[e] = wsf + off;
            off = (off + n + 63) & ~63;
            base += n;
        }
    }
    tab.total = base;
    transpose_w_k<<<(base + THREADS - 1) / THREADS, THREADS, 0, stream>>>(tab, wsf);

    int B = 4;
    while (B > 1 && ws_size < ((size_t)TW_FLOATS + (size_t)B * SLOT) * sizeof(float)) B >>= 1;

    auto run_all = [&](int Bc, float* slot, int SB,
                       const float* xin, int xbs, float* outp, int obs) {
        float* S0 = slot;
        float* S1 = S0 + 36 * A1;
        float* S2 = S1 + 18 * A1;
        float* P  = S2 + 2 * A1;
        float* L1 = S1 + 10 * A1;
        float* L2 = S0 + 32 * A1;
        auto gs = [&](int n, int px, int z) { return dim3((n / (px * THREADS)) * Bc * z); };
        auto gp = [&](int n, int px) { return dim3(n / (px * THREADS), Bc); };
        auto g1 = [&](int n) { return dim3((n + THREADS - 1) / THREADS, Bc); };

        // ---- level 1 down ----
        conv_sl_k<4, 18, 5, false, 4><<<gs(A1, 4, 1), THREADS, 0, stream>>>(xin, tw[0], eo1_b1, S1, H1, 9, xbs, SB, Bc, 1);
        conv_sl_k<18, 12, 5, false, 8><<<gs(A1, 8, 3), THREADS, 0, stream>>>(S1, tw[1], eo1_b2, S0, H1, 9, SB, SB, Bc, 3);
        dconv_k<4, 2><<<g1(A1), THREADS, 0, stream>>>(xin, S0, tw[26], tw[27], S2, H1, 9, xbs, SB, SB);
        conv_k<2, 4, 3, true, 4><<<gp(A1, 4), THREADS, 0, stream>>>(S2, tw[4], c1d_b1, S1, H1, 9, SB, SB);
        conv_k<4, 8, 3, true, 4><<<gp(A1, 4), THREADS, 0, stream>>>(S1, tw[5], c1d_b2, L1, H1, 9, SB, SB);
        avgpool_k<<<g1(8 * A2), THREADS, 0, stream>>>(L1, P, 8 * A2, 16, 8, SB, SB);

        // ---- level 2 down ----
        conv_sl_k<8, 6, 5, false, 4><<<gs(A2, 4, 3), THREADS, 0, stream>>>(P, tw[6], eo2_b1, S1, H2, 8, SB, SB, Bc, 3);
        conv_sl_k<18, 12, 5, false, 4><<<gs(A2, 4, 3), THREADS, 0, stream>>>(S1, tw[9], eo2_b2, S0, H2, 8, SB, SB, Bc, 3);
        dconv_k<8, 8><<<g1(A2), THREADS, 0, stream>>>(P, S0, tw[28], tw[29], S2, H2, 8, SB, SB, SB);
        conv_k<8, 12, 3, true, 2><<<gp(A2, 2), THREADS, 0, stream>>>(S2, tw[12], c2d_b1, S1, H2, 8, SB, SB);
        conv_k<12, 16, 3, true, 2><<<gp(A2, 2), THREADS, 0, stream>>>(S1, tw[13], c2d_b2, L2, H2, 8, SB, SB);
        avgpool_k<<<g1(16 * A3), THREADS, 0, stream>>>(L2, P, 16 * A3, 14, 7, SB, SB);

        // ---- level 3 (bottleneck) ----
        conv_k<16, 18, 5, false, 2><<<gp(A3, 2), THREADS, 0, stream>>>(P, tw[14], eo3_b1, S1, H3, 7, SB, SB);
        conv_sl_k<18, 12, 5, false, 4><<<gs(A3, 4, 3), THREADS, 0, stream>>>(S1, tw[15], eo3_b2, S0, H3, 7, SB, SB, Bc, 3);
        dconv_k<16, 16><<<g1(A3), THREADS, 0, stream>>>(P, S0, tw[30], tw[31], S2, H3, 7, SB, SB, SB);
        conv_k<16, 14, 3, true, 2><<<gp(A3, 2), THREADS, 0, stream>>>(S2, tw[18], c3d_b1, S1, H3, 7, SB, SB);
        conv_k<14, 12, 3, true, 2><<<gp(A3, 2), THREADS, 0, stream>>>(S1, tw[19], c3d_b2, S2, H3, 7, SB, SB);

        // ---- up path level 2 ----
        up2x_k<<<g1(12 * A2), THREADS, 0, stream>>>(S2, S0, 12 * A2, 16, 8, H3, SB, SB);
        conv_k<12, 12, 3, true, 2><<<gp(A2, 2), THREADS, 0, stream>>>(S0, tw[20], up2_b, S1, H2, 8, SB, SB);
        conv2in_k<12, 16, 16, 3, true, 2><<<gp(A2, 2), THREADS, 0, stream>>>(S1, L2, tw[21], c2u_b1, S0, H2, 8, SB, SB, SB);
        conv_k<16, 8, 3, true, 2><<<gp(A2, 2), THREADS, 0, stream>>>(S0, tw[22], c2u_b2, S2, H2, 8, SB, SB);

        // ---- up path level 1 ----
        up2x_k<<<g1(8 * A1), THREADS, 0, stream>>>(S2, S0, 8 * A1, 18, 9, H2, SB, SB);
        conv_k<8, 8, 3, true, 4><<<gp(A1, 4), THREADS, 0, stream>>>(S0, tw[23], up1_b, S0 + 8 * A1, H1, 9, SB, SB);
        conv2in_k<8, 8, 8, 3, true, 4><<<gp(A1, 4), THREADS, 0, stream>>>(S0 + 8 * A1, L1, tw[24], c1u_b1, S1, H1, 9, SB, SB, SB);
        conv_k<8, 2, 3, true, 4><<<gp(A1, 4), THREADS, 0, stream>>>(S1, tw[25], c1u_b2, outp, H1, 9, SB, obs);
    };

    for (int g = 0; g < 4; g += B)
        run_all(B, wsf + TW_FLOATS, SLOT,
                x + (size_t)g * 4 * A1, 4 * A1,
                out + (size_t)g * 2 * A1, 2 * A1);
}